// Round 1
// baseline (1247.678 us; speedup 1.0000x reference)
//
#include <hip/hip_runtime.h>
#include <math.h>

#define ALPHA 0.2f
#define NEGV  -9e15f
#define EPSV  1e-5f

constexpr int B_ = 2, N_ = 4096, F_ = 256, H_ = 1024;
constexpr int SPLIT_ = 16;

// ---------------- fp32 tiled GEMM: C[M,Nc] = A[M,K] @ B[K,Nc] (+bias)(+relu) ----
// BM=128, BN=64, BK=16, block=256 (tx=tid&15 -> 4 cols, ty=tid>>4 -> 8 rows)
__global__ __launch_bounds__(256) void gemm_kernel(
    const float* __restrict__ A, const float* __restrict__ Bm,
    const float* __restrict__ bias, float* __restrict__ C,
    int M, int Nc, int K, int relu)
{
    __shared__ float As[16][128];
    __shared__ float Bs[16][64];
    const int tid = threadIdx.x;
    const int tx = tid & 15, ty = tid >> 4;
    const int row0 = blockIdx.y * 128;
    const int col0 = blockIdx.x * 64;

    float acc[8][4] = {};

    for (int k0 = 0; k0 < K; k0 += 16) {
        // stage A tile (128x16), transposed into As[k][row]
        {
            const int r = tid >> 2;      // 0..63
            const int kq = tid & 3;      // 0..3
            #pragma unroll
            for (int h = 0; h < 2; ++h) {
                const int rr = h * 64 + r;
                const float4 v = *(const float4*)&A[(size_t)(row0 + rr) * K + k0 + kq * 4];
                As[kq * 4 + 0][rr] = v.x;
                As[kq * 4 + 1][rr] = v.y;
                As[kq * 4 + 2][rr] = v.z;
                As[kq * 4 + 3][rr] = v.w;
            }
            // stage B tile (16x64)
            const int kk = tid >> 4;     // 0..15
            const int cq = tid & 15;     // 0..15
            const float4 v = *(const float4*)&Bm[(size_t)(k0 + kk) * Nc + col0 + cq * 4];
            *(float4*)&Bs[kk][cq * 4] = v;
        }
        __syncthreads();
        #pragma unroll
        for (int kk = 0; kk < 16; ++kk) {
            const float4 b4 = *(const float4*)&Bs[kk][tx * 4];
            const float4 a0 = *(const float4*)&As[kk][ty * 8];
            const float4 a1 = *(const float4*)&As[kk][ty * 8 + 4];
            const float ar[8] = {a0.x, a0.y, a0.z, a0.w, a1.x, a1.y, a1.z, a1.w};
            #pragma unroll
            for (int r = 0; r < 8; ++r) {
                acc[r][0] += ar[r] * b4.x;
                acc[r][1] += ar[r] * b4.y;
                acc[r][2] += ar[r] * b4.z;
                acc[r][3] += ar[r] * b4.w;
            }
        }
        __syncthreads();
    }

    float4 bv = make_float4(0.f, 0.f, 0.f, 0.f);
    if (bias) bv = *(const float4*)&bias[col0 + tx * 4];
    #pragma unroll
    for (int r = 0; r < 8; ++r) {
        float4 o;
        o.x = acc[r][0] + bv.x;
        o.y = acc[r][1] + bv.y;
        o.z = acc[r][2] + bv.z;
        o.w = acc[r][3] + bv.w;
        if (relu) {
            o.x = fmaxf(o.x, 0.f); o.y = fmaxf(o.y, 0.f);
            o.z = fmaxf(o.z, 0.f); o.w = fmaxf(o.w, 0.f);
        }
        *(float4*)&C[(size_t)(row0 + ty * 8 + r) * Nc + col0 + tx * 4] = o;
    }
}

// ---------------- Wh1/Wh2: per-row dot(Wh[row,:], a[:256]) and a[256:512] -------
__global__ __launch_bounds__(256) void wh12_kernel(
    const float* __restrict__ Wh, const float* __restrict__ a,
    float* __restrict__ Wh1, float* __restrict__ Wh2)
{
    const int wid = threadIdx.x >> 6, lane = threadIdx.x & 63;
    const int row = blockIdx.x * 4 + wid;
    const float4 w  = *(const float4*)&Wh[(size_t)row * F_ + lane * 4];
    const float4 u1 = *(const float4*)&a[lane * 4];
    const float4 u2 = *(const float4*)&a[F_ + lane * 4];
    float s1 = w.x * u1.x + w.y * u1.y + w.z * u1.z + w.w * u1.w;
    float s2 = w.x * u2.x + w.y * u2.y + w.z * u2.z + w.w * u2.w;
    #pragma unroll
    for (int off = 32; off > 0; off >>= 1) {
        s1 += __shfl_down(s1, off);
        s2 += __shfl_down(s2, off);
    }
    if (lane == 0) { Wh1[row] = s1; Wh2[row] = s2; }
}

// ---------------- column softmax stats (partial, split over i) ------------------
// grid (N/256, SPLIT, B), block 256; thread handles one column j over 256 rows.
__global__ __launch_bounds__(256) void colstats_kernel(
    const int* __restrict__ adj, const float* __restrict__ Wh1,
    const float* __restrict__ Wh2, float* __restrict__ pM, float* __restrict__ pS)
{
    const int j = blockIdx.x * 256 + threadIdx.x;
    const int sp = blockIdx.y;
    const int b = blockIdx.z;
    const int i0 = sp * (N_ / SPLIT_);
    const int* __restrict__ ap = adj + ((size_t)b * N_ + i0) * N_ + j;
    const float* __restrict__ w1p = Wh1 + b * N_ + i0;
    const float w2 = Wh2[b * N_ + j];
    float m = -3.4e38f, s = 0.f;
    for (int ii = 0; ii < N_ / SPLIT_; ++ii) {
        float e = w1p[ii] + w2;
        e = e > 0.f ? e : ALPHA * e;
        const float x = (ap[(size_t)ii * N_] > 0) ? e : NEGV;
        const float nm = fmaxf(m, x);
        s = s * __expf(m - nm) + __expf(x - nm);
        m = nm;
    }
    pM[((size_t)b * SPLIT_ + sp) * N_ + j] = m;
    pS[((size_t)b * SPLIT_ + sp) * N_ + j] = s;
}

__global__ __launch_bounds__(256) void colfin_kernel(
    const float* __restrict__ pM, const float* __restrict__ pS,
    float* __restrict__ Mcol, float* __restrict__ Sinv)
{
    const int j = blockIdx.x * 256 + threadIdx.x;
    const int b = blockIdx.y;
    float m = -3.4e38f;
    #pragma unroll
    for (int s = 0; s < SPLIT_; ++s)
        m = fmaxf(m, pM[((size_t)b * SPLIT_ + s) * N_ + j]);
    float sum = 0.f;
    #pragma unroll
    for (int s = 0; s < SPLIT_; ++s)
        sum += pS[((size_t)b * SPLIT_ + s) * N_ + j] *
               __expf(pM[((size_t)b * SPLIT_ + s) * N_ + j] - m);
    Mcol[b * N_ + j] = m;
    Sinv[b * N_ + j] = 1.0f / sum;
}

// ---------------- attention matmul: out[i,f] = sum_j P[i,j] * Wh[j,f] -----------
// block = 512 threads; 32 rows/block; P tile (32 x 64) regenerated in LDS.
// tx = t&63 -> 4 f's (f = tx*4..+3); rg = t>>6 -> 4 rows (r = rg*4..+3).
__global__ __launch_bounds__(512) void att_kernel(
    const int* __restrict__ adj, const float* __restrict__ Wh,
    const float* __restrict__ Wh1, const float* __restrict__ Wh2,
    const float* __restrict__ Mcol, const float* __restrict__ Sinv,
    float* __restrict__ out)
{
    __shared__ float Ps[32][72];   // row stride 72 floats (288B, 16B aligned)
    const int b = blockIdx.y;
    const int i0 = blockIdx.x * 32;
    const int t = threadIdx.x;
    const int jj = t & 63;   // doubles as f-group in compute phase
    const int rg = t >> 6;   // 0..7

    const float* __restrict__ WhB = Wh + (size_t)b * N_ * F_;
    float w1[4];
    #pragma unroll
    for (int rr = 0; rr < 4; ++rr) w1[rr] = Wh1[b * N_ + i0 + rg * 4 + rr];

    float acc[4][4] = {};

    for (int j0 = 0; j0 < N_; j0 += 64) {
        // --- generate P tile ---
        {
            const int j = j0 + jj;
            const float w2 = Wh2[b * N_ + j];
            const float mj = Mcol[b * N_ + j];
            const float si = Sinv[b * N_ + j];
            const int* __restrict__ ap = adj + ((size_t)b * N_ + i0 + rg * 4) * N_ + j;
            #pragma unroll
            for (int rr = 0; rr < 4; ++rr) {
                const int av = ap[(size_t)rr * N_];
                float e = w1[rr] + w2;
                e = e > 0.f ? e : ALPHA * e;
                const float x = (av > 0) ? e : NEGV;
                Ps[rg * 4 + rr][jj] = __expf(x - mj) * si;
            }
        }
        __syncthreads();
        // --- multiply against Wh tile ---
        for (int q = 0; q < 64; q += 4) {
            const float4 p0 = *(const float4*)&Ps[rg * 4 + 0][q];
            const float4 p1 = *(const float4*)&Ps[rg * 4 + 1][q];
            const float4 p2 = *(const float4*)&Ps[rg * 4 + 2][q];
            const float4 p3 = *(const float4*)&Ps[rg * 4 + 3][q];
            #pragma unroll
            for (int u = 0; u < 4; ++u) {
                const float4 w = *(const float4*)&WhB[(size_t)(j0 + q + u) * F_ + jj * 4];
                const float f0 = (&p0.x)[u], f1 = (&p1.x)[u];
                const float f2 = (&p2.x)[u], f3 = (&p3.x)[u];
                acc[0][0] += f0 * w.x; acc[0][1] += f0 * w.y; acc[0][2] += f0 * w.z; acc[0][3] += f0 * w.w;
                acc[1][0] += f1 * w.x; acc[1][1] += f1 * w.y; acc[1][2] += f1 * w.z; acc[1][3] += f1 * w.w;
                acc[2][0] += f2 * w.x; acc[2][1] += f2 * w.y; acc[2][2] += f2 * w.z; acc[2][3] += f2 * w.w;
                acc[3][0] += f3 * w.x; acc[3][1] += f3 * w.y; acc[3][2] += f3 * w.z; acc[3][3] += f3 * w.w;
            }
        }
        __syncthreads();
    }
    #pragma unroll
    for (int rr = 0; rr < 4; ++rr) {
        const float4 o = make_float4(acc[rr][0], acc[rr][1], acc[rr][2], acc[rr][3]);
        *(float4*)&out[((size_t)b * N_ + i0 + rg * 4 + rr) * F_ + jj * 4] = o;
    }
}

// ---------------- residual add + LayerNorm over F=256 --------------------------
__global__ __launch_bounds__(256) void addln_kernel(
    const float* __restrict__ X, const float* __restrict__ Y,
    const float* __restrict__ g, const float* __restrict__ bta,
    float* __restrict__ out)
{
    const int row = blockIdx.x;
    const int t = threadIdx.x;
    const size_t idx = (size_t)row * F_ + t;
    const float v = X[idx] + Y[idx];
    float s1 = v, s2 = v * v;
    #pragma unroll
    for (int off = 32; off > 0; off >>= 1) {
        s1 += __shfl_down(s1, off);
        s2 += __shfl_down(s2, off);
    }
    __shared__ float r1[4], r2[4];
    __shared__ float mu_s, rs_s;
    const int wid = t >> 6, lane = t & 63;
    if (lane == 0) { r1[wid] = s1; r2[wid] = s2; }
    __syncthreads();
    if (t == 0) {
        const float a = r1[0] + r1[1] + r1[2] + r1[3];
        const float q = r2[0] + r2[1] + r2[2] + r2[3];
        const float mu = a * (1.f / F_);
        const float var = q * (1.f / F_) - mu * mu;
        mu_s = mu;
        rs_s = rsqrtf(var + EPSV);
    }
    __syncthreads();
    out[idx] = (v - mu_s) * rs_s * g[t] + bta[t];
}

// -------------------------------------------------------------------------------
extern "C" void kernel_launch(void* const* d_in, const int* in_sizes, int n_in,
                              void* d_out, int out_size, void* d_ws, size_t ws_size,
                              hipStream_t stream)
{
    const float* x     = (const float*)d_in[0];
    const int*   adj   = (const int*)d_in[1];
    const float* W1    = (const float*)d_in[2];
    const float* a1    = (const float*)d_in[3];
    const float* W2    = (const float*)d_in[4];
    const float* a2    = (const float*)d_in[5];
    const float* w_ff1 = (const float*)d_in[6];
    const float* b_ff1 = (const float*)d_in[7];
    const float* w_ff2 = (const float*)d_in[8];
    const float* b_ff2 = (const float*)d_in[9];
    const float* g_ln1 = (const float*)d_in[10];
    const float* b_ln1 = (const float*)d_in[11];
    const float* g_ln2 = (const float*)d_in[12];
    const float* b_ln2 = (const float*)d_in[13];
    float* out = (float*)d_out;

    const int Rtot = B_ * N_;             // 8192 rows
    float* ws = (float*)d_ws;
    float* Wh_buf = ws;                                   // 2,097,152 f
    float* g1out  = ws + 2097152;                         // 2,097,152 f
    float* ln1    = ws + 4194304;                         // 2,097,152 f
    float* mid    = ws + 6291456;                         // 8,388,608 f
    float* Wh1v   = ws + 14680064;                        // 8192 f
    float* Wh2v   = Wh1v + 8192;
    float* Mcol   = Wh2v + 8192;
    float* Sinv   = Mcol + 8192;
    float* pM     = Sinv + 8192;                          // 131072 f
    float* pS     = pM + (size_t)B_ * SPLIT_ * N_;        // 131072 f

    const dim3 gemmB(256);
    const dim3 statsG(N_ / 256, SPLIT_, B_);
    const dim3 finG(N_ / 256, B_);
    const dim3 attG(N_ / 32, B_);

    // ===== GAT layer 1 =====
    gemm_kernel<<<dim3(F_ / 64, Rtot / 128), gemmB, 0, stream>>>(x, W1, nullptr, Wh_buf, Rtot, F_, F_, 0);
    wh12_kernel<<<Rtot / 4, 256, 0, stream>>>(Wh_buf, a1, Wh1v, Wh2v);
    colstats_kernel<<<statsG, 256, 0, stream>>>(adj, Wh1v, Wh2v, pM, pS);
    colfin_kernel<<<finG, 256, 0, stream>>>(pM, pS, Mcol, Sinv);
    att_kernel<<<attG, 512, 0, stream>>>(adj, Wh_buf, Wh1v, Wh2v, Mcol, Sinv, g1out);

    // ===== GAT layer 2 =====
    gemm_kernel<<<dim3(F_ / 64, Rtot / 128), gemmB, 0, stream>>>(g1out, W2, nullptr, Wh_buf, Rtot, F_, F_, 0);
    wh12_kernel<<<Rtot / 4, 256, 0, stream>>>(Wh_buf, a2, Wh1v, Wh2v);
    colstats_kernel<<<statsG, 256, 0, stream>>>(adj, Wh1v, Wh2v, pM, pS);
    colfin_kernel<<<finG, 256, 0, stream>>>(pM, pS, Mcol, Sinv);
    att_kernel<<<attG, 512, 0, stream>>>(adj, Wh_buf, Wh1v, Wh2v, Mcol, Sinv, g1out);

    // ===== LN1(x + gat2) =====
    addln_kernel<<<Rtot, 256, 0, stream>>>(x, g1out, g_ln1, b_ln1, ln1);

    // ===== FFN =====
    gemm_kernel<<<dim3(H_ / 64, Rtot / 128), gemmB, 0, stream>>>(ln1, w_ff1, b_ff1, mid, Rtot, H_, F_, 1);
    gemm_kernel<<<dim3(F_ / 64, Rtot / 128), gemmB, 0, stream>>>(mid, w_ff2, b_ff2, out, Rtot, F_, H_, 0);

    // ===== LN2(ln1 + ff) -> out (in-place on out) =====
    addln_kernel<<<Rtot, 256, 0, stream>>>(ln1, out, g_ln2, b_ln2, out);
}

// Round 2
// 1127.916 us; speedup vs baseline: 1.1062x; 1.1062x over previous
//
#include <hip/hip_runtime.h>
#include <math.h>

#define ALPHA 0.2f
#define NEGV  -9e15f
#define EPSV  1e-5f

constexpr int B_ = 2, N_ = 4096, F_ = 256, H_ = 1024;
constexpr int SPLIT_ = 16;

typedef __attribute__((ext_vector_type(4))) float f32x4;
typedef __attribute__((ext_vector_type(8))) short s16x8;

__device__ __forceinline__ unsigned short f2bf(float f) {
    unsigned u = __builtin_bit_cast(unsigned, f);
    u += 0x7fffu + ((u >> 16) & 1u);
    return (unsigned short)(u >> 16);
}

// ---------------- fp32 tiled GEMM: C[M,Nc] = A[M,K] @ B[K,Nc] (+bias)(+relu) ----
__global__ __launch_bounds__(256) void gemm_kernel(
    const float* __restrict__ A, const float* __restrict__ Bm,
    const float* __restrict__ bias, float* __restrict__ C,
    int M, int Nc, int K, int relu)
{
    __shared__ float As[16][128];
    __shared__ float Bs[16][64];
    const int tid = threadIdx.x;
    const int tx = tid & 15, ty = tid >> 4;
    const int row0 = blockIdx.y * 128;
    const int col0 = blockIdx.x * 64;

    float acc[8][4] = {};

    for (int k0 = 0; k0 < K; k0 += 16) {
        {
            const int r = tid >> 2;
            const int kq = tid & 3;
            #pragma unroll
            for (int h = 0; h < 2; ++h) {
                const int rr = h * 64 + r;
                const float4 v = *(const float4*)&A[(size_t)(row0 + rr) * K + k0 + kq * 4];
                As[kq * 4 + 0][rr] = v.x;
                As[kq * 4 + 1][rr] = v.y;
                As[kq * 4 + 2][rr] = v.z;
                As[kq * 4 + 3][rr] = v.w;
            }
            const int kk = tid >> 4;
            const int cq = tid & 15;
            const float4 v = *(const float4*)&Bm[(size_t)(k0 + kk) * Nc + col0 + cq * 4];
            *(float4*)&Bs[kk][cq * 4] = v;
        }
        __syncthreads();
        #pragma unroll
        for (int kk = 0; kk < 16; ++kk) {
            const float4 b4 = *(const float4*)&Bs[kk][tx * 4];
            const float4 a0 = *(const float4*)&As[kk][ty * 8];
            const float4 a1 = *(const float4*)&As[kk][ty * 8 + 4];
            const float ar[8] = {a0.x, a0.y, a0.z, a0.w, a1.x, a1.y, a1.z, a1.w};
            #pragma unroll
            for (int r = 0; r < 8; ++r) {
                acc[r][0] += ar[r] * b4.x;
                acc[r][1] += ar[r] * b4.y;
                acc[r][2] += ar[r] * b4.z;
                acc[r][3] += ar[r] * b4.w;
            }
        }
        __syncthreads();
    }

    float4 bv = make_float4(0.f, 0.f, 0.f, 0.f);
    if (bias) bv = *(const float4*)&bias[col0 + tx * 4];
    #pragma unroll
    for (int r = 0; r < 8; ++r) {
        float4 o;
        o.x = acc[r][0] + bv.x;
        o.y = acc[r][1] + bv.y;
        o.z = acc[r][2] + bv.z;
        o.w = acc[r][3] + bv.w;
        if (relu) {
            o.x = fmaxf(o.x, 0.f); o.y = fmaxf(o.y, 0.f);
            o.z = fmaxf(o.z, 0.f); o.w = fmaxf(o.w, 0.f);
        }
        *(float4*)&C[(size_t)(row0 + ty * 8 + r) * Nc + col0 + tx * 4] = o;
    }
}

// ---------------- Wh1/Wh2 row dots ---------------------------------------------
__global__ __launch_bounds__(256) void wh12_kernel(
    const float* __restrict__ Wh, const float* __restrict__ a,
    float* __restrict__ Wh1, float* __restrict__ Wh2)
{
    const int wid = threadIdx.x >> 6, lane = threadIdx.x & 63;
    const int row = blockIdx.x * 4 + wid;
    const float4 w  = *(const float4*)&Wh[(size_t)row * F_ + lane * 4];
    const float4 u1 = *(const float4*)&a[lane * 4];
    const float4 u2 = *(const float4*)&a[F_ + lane * 4];
    float s1 = w.x * u1.x + w.y * u1.y + w.z * u1.z + w.w * u1.w;
    float s2 = w.x * u2.x + w.y * u2.y + w.z * u2.z + w.w * u2.w;
    #pragma unroll
    for (int off = 32; off > 0; off >>= 1) {
        s1 += __shfl_down(s1, off);
        s2 += __shfl_down(s2, off);
    }
    if (lane == 0) { Wh1[row] = s1; Wh2[row] = s2; }
}

// ---------------- column softmax stats; layer1 reads adj + writes bitmask ------
__global__ __launch_bounds__(256) void colstats2_kernel(
    const int* __restrict__ adj, const unsigned long long* __restrict__ maskIn,
    unsigned long long* __restrict__ maskOut,
    const float* __restrict__ Wh1, const float* __restrict__ Wh2,
    float* __restrict__ pM, float* __restrict__ pS)
{
    const int t = threadIdx.x;
    const int j = blockIdx.x * 256 + t;
    const int sp = blockIdx.y;
    const int b = blockIdx.z;
    const int i0 = sp * (N_ / SPLIT_);
    const int w = t >> 6, lane = t & 63;
    const float w2 = Wh2[b * N_ + j];
    const float* __restrict__ w1p = Wh1 + b * N_ + i0;
    float m = -3.4e38f, s = 0.f;
    for (int ii = 0; ii < N_ / SPLIT_; ++ii) {
        const int i = i0 + ii;
        bool act;
        if (adj) {
            act = adj[((size_t)b * N_ + i) * N_ + j] > 0;
            const unsigned long long bm = __ballot(act);
            if (lane == 0)
                maskOut[((size_t)b * N_ + i) * (N_ / 64) + blockIdx.x * 4 + w] = bm;
        } else {
            const unsigned long long mw =
                maskIn[((size_t)b * N_ + i) * (N_ / 64) + blockIdx.x * 4 + w];
            act = (mw >> (j & 63)) & 1ull;
        }
        float e = w1p[ii] + w2;
        e = fmaxf(e, ALPHA * e);
        const float x = act ? e : NEGV;
        const float nm = fmaxf(m, x);
        s = s * __expf(m - nm) + __expf(x - nm);
        m = nm;
    }
    pM[((size_t)b * SPLIT_ + sp) * N_ + j] = m;
    pS[((size_t)b * SPLIT_ + sp) * N_ + j] = s;
}

__global__ __launch_bounds__(256) void colfin_kernel(
    const float* __restrict__ pM, const float* __restrict__ pS,
    float* __restrict__ Mcol, float* __restrict__ Sinv)
{
    const int j = blockIdx.x * 256 + threadIdx.x;
    const int b = blockIdx.y;
    float m = -3.4e38f;
    #pragma unroll
    for (int s = 0; s < SPLIT_; ++s)
        m = fmaxf(m, pM[((size_t)b * SPLIT_ + s) * N_ + j]);
    float sum = 0.f;
    #pragma unroll
    for (int s = 0; s < SPLIT_; ++s)
        sum += pS[((size_t)b * SPLIT_ + s) * N_ + j] *
               __expf(pM[((size_t)b * SPLIT_ + s) * N_ + j] - m);
    Mcol[b * N_ + j] = m;
    Sinv[b * N_ + j] = 1.0f / sum;
}

// ---------------- transpose + bf16 convert: Wh[b][j][f] -> Wh_t[b][f][j] -------
__global__ __launch_bounds__(256) void transp_kernel(
    const float* __restrict__ Wh, unsigned short* __restrict__ Wht)
{
    __shared__ float T[64][65];
    const int t = threadIdx.x;
    const int j0 = blockIdx.x * 64, f0 = blockIdx.y * 64, b = blockIdx.z;
    #pragma unroll
    for (int s = 0; s < 4; ++s) {
        const int jr = s * 16 + (t >> 4);
        const int c = t & 15;
        const float4 v = *(const float4*)&Wh[((size_t)b * N_ + j0 + jr) * F_ + f0 + c * 4];
        T[jr][c * 4 + 0] = v.x; T[jr][c * 4 + 1] = v.y;
        T[jr][c * 4 + 2] = v.z; T[jr][c * 4 + 3] = v.w;
    }
    __syncthreads();
    #pragma unroll
    for (int s = 0; s < 4; ++s) {
        const int fr = s * 16 + (t >> 4);
        const int c = t & 15;
        ushort4 o;
        o.x = f2bf(T[c * 4 + 0][fr]);
        o.y = f2bf(T[c * 4 + 1][fr]);
        o.z = f2bf(T[c * 4 + 2][fr]);
        o.w = f2bf(T[c * 4 + 3][fr]);
        *(ushort4*)&Wht[((size_t)b * F_ + f0 + fr) * N_ + j0 + c * 4] = o;
    }
}

// ---------------- fused attention matmul via MFMA bf16 -------------------------
// grid (N/32, B), block 256 (4 waves). Out tile 32 i x 256 f; K-loop over j.
// Wave w owns f-range [w*64, w*64+64). A (P) frags shared via LDS.
__global__ __launch_bounds__(256) void att_mfma_kernel(
    const unsigned char* __restrict__ maskB, const unsigned short* __restrict__ Wht,
    const float* __restrict__ Wh1, const float* __restrict__ Wh2,
    const float* __restrict__ Mcol, const float* __restrict__ Sinv,
    float* __restrict__ out)
{
    __shared__ unsigned short Bs[256 * 40];  // [f][j] tile, row stride 40 (80B)
    __shared__ unsigned short Ps[32 * 40];   // [i][j] tile, row stride 40

    const int t = threadIdx.x;
    const int w = t >> 6, l = t & 63;
    const int quad = l >> 4, l15 = l & 15;
    const int b = blockIdx.y;
    const int i0 = blockIdx.x * 32;

    // P-gen assignment: lane computes 4 j's for one i
    const int pi = t & 31;       // i offset within tile
    const int pj = t >> 5;       // 0..7 -> j sub-range pj*4..+3
    const float w1i = Wh1[b * N_ + i0 + pi];
    const unsigned char* __restrict__ mrow =
        maskB + ((size_t)b * N_ + i0 + pi) * (N_ / 8);

    f32x4 acc[2][4];
    #pragma unroll
    for (int it = 0; it < 2; ++it)
        #pragma unroll
        for (int ft = 0; ft < 4; ++ft)
            acc[it][ft] = (f32x4)(0.f);

    const unsigned short* __restrict__ WhtB = Wht + (size_t)b * F_ * N_;
    const float* __restrict__ w2B = Wh2 + b * N_;
    const float* __restrict__ mB  = Mcol + b * N_;
    const float* __restrict__ sB  = Sinv + b * N_;

    for (int j0 = 0; j0 < N_; j0 += 32) {
        // ---- stage B tile: Wh_t[f][j0..j0+31] for all 256 f ----
        #pragma unroll
        for (int s = 0; s < 4; ++s) {
            const int idx = t + s * 256;
            const int f = idx >> 2, part = idx & 3;
            const s16x8 v = *(const s16x8*)&WhtB[(size_t)f * N_ + j0 + part * 8];
            *(s16x8*)&Bs[f * 40 + part * 8] = v;
        }
        // ---- generate P tile (32 i x 32 j), bf16, A-frag friendly layout ----
        {
            const unsigned mbyte = mrow[(j0 >> 3) + (pj >> 1)];
            const unsigned shift = (pj & 1) * 4;
            const float4 w2v = *(const float4*)&w2B[j0 + pj * 4];
            const float4 mv  = *(const float4*)&mB[j0 + pj * 4];
            const float4 sv  = *(const float4*)&sB[j0 + pj * 4];
            unsigned short pv[4];
            #pragma unroll
            for (int u = 0; u < 4; ++u) {
                const float xw = w1i + (&w2v.x)[u];
                const float e = fmaxf(xw, ALPHA * xw);
                const float x2 = ((mbyte >> (shift + u)) & 1u) ? e : NEGV;
                const float p = __expf(x2 - (&mv.x)[u]) * (&sv.x)[u];
                pv[u] = f2bf(p);
            }
            *(ushort4*)&Ps[pi * 40 + pj * 4] =
                make_ushort4(pv[0], pv[1], pv[2], pv[3]);
        }
        __syncthreads();
        // ---- MFMA ----
        const s16x8 a0 = *(const s16x8*)&Ps[l15 * 40 + quad * 8];
        const s16x8 a1 = *(const s16x8*)&Ps[(16 + l15) * 40 + quad * 8];
        #pragma unroll
        for (int ft = 0; ft < 4; ++ft) {
            const int f = w * 64 + ft * 16 + l15;
            const s16x8 bf = *(const s16x8*)&Bs[f * 40 + quad * 8];
            acc[0][ft] = __builtin_amdgcn_mfma_f32_16x16x32_bf16(a0, bf, acc[0][ft], 0, 0, 0);
            acc[1][ft] = __builtin_amdgcn_mfma_f32_16x16x32_bf16(a1, bf, acc[1][ft], 0, 0, 0);
        }
        __syncthreads();
    }

    // ---- epilogue: C/D layout col=lane&15, row=quad*4+reg ----
    #pragma unroll
    for (int it = 0; it < 2; ++it)
        #pragma unroll
        for (int ft = 0; ft < 4; ++ft) {
            const int f = w * 64 + ft * 16 + l15;
            #pragma unroll
            for (int rr = 0; rr < 4; ++rr) {
                const int row = i0 + it * 16 + quad * 4 + rr;
                out[((size_t)b * N_ + row) * F_ + f] = acc[it][ft][rr];
            }
        }
}

// ---------------- residual add + LayerNorm over F=256 --------------------------
__global__ __launch_bounds__(256) void addln_kernel(
    const float* __restrict__ X, const float* __restrict__ Y,
    const float* __restrict__ g, const float* __restrict__ bta,
    float* __restrict__ out)
{
    const int row = blockIdx.x;
    const int t = threadIdx.x;
    const size_t idx = (size_t)row * F_ + t;
    const float v = X[idx] + Y[idx];
    float s1 = v, s2 = v * v;
    #pragma unroll
    for (int off = 32; off > 0; off >>= 1) {
        s1 += __shfl_down(s1, off);
        s2 += __shfl_down(s2, off);
    }
    __shared__ float r1[4], r2[4];
    __shared__ float mu_s, rs_s;
    const int wid = t >> 6, lane = t & 63;
    if (lane == 0) { r1[wid] = s1; r2[wid] = s2; }
    __syncthreads();
    if (t == 0) {
        const float a = r1[0] + r1[1] + r1[2] + r1[3];
        const float q = r2[0] + r2[1] + r2[2] + r2[3];
        const float mu = a * (1.f / F_);
        const float var = q * (1.f / F_) - mu * mu;
        mu_s = mu;
        rs_s = rsqrtf(var + EPSV);
    }
    __syncthreads();
    out[idx] = (v - mu_s) * rs_s * g[t] + bta[t];
}

// -------------------------------------------------------------------------------
extern "C" void kernel_launch(void* const* d_in, const int* in_sizes, int n_in,
                              void* d_out, int out_size, void* d_ws, size_t ws_size,
                              hipStream_t stream)
{
    const float* x     = (const float*)d_in[0];
    const int*   adj   = (const int*)d_in[1];
    const float* W1    = (const float*)d_in[2];
    const float* a1    = (const float*)d_in[3];
    const float* W2    = (const float*)d_in[4];
    const float* a2    = (const float*)d_in[5];
    const float* w_ff1 = (const float*)d_in[6];
    const float* b_ff1 = (const float*)d_in[7];
    const float* w_ff2 = (const float*)d_in[8];
    const float* b_ff2 = (const float*)d_in[9];
    const float* g_ln1 = (const float*)d_in[10];
    const float* b_ln1 = (const float*)d_in[11];
    const float* g_ln2 = (const float*)d_in[12];
    const float* b_ln2 = (const float*)d_in[13];
    float* out = (float*)d_out;

    const int Rtot = B_ * N_;
    float* ws = (float*)d_ws;
    float* Wh_buf = ws;                                   // 2,097,152 f
    float* g1out  = ws + 2097152;                         // 2,097,152 f
    float* ln1    = ws + 4194304;                         // 2,097,152 f
    float* mid    = ws + 6291456;                         // 8,388,608 f (FFN only)
    // Wh_t (bf16) and mask alias the front of `mid` — lifetimes disjoint w/ FFN
    unsigned short* Wht = (unsigned short*)(ws + 6291456);          // 2,097,152 bf16
    unsigned long long* mask = (unsigned long long*)(ws + 7340032); // 4 MB bits
    unsigned char* maskB = (unsigned char*)mask;
    float* Wh1v = ws + 14680064;
    float* Wh2v = Wh1v + 8192;
    float* Mcol = Wh2v + 8192;
    float* Sinv = Mcol + 8192;
    float* pM   = Sinv + 8192;                            // 131072 f
    float* pS   = pM + (size_t)B_ * SPLIT_ * N_;          // 131072 f

    const dim3 statsG(N_ / 256, SPLIT_, B_);
    const dim3 finG(N_ / 256, B_);
    const dim3 attG(N_ / 32, B_);
    const dim3 trG(N_ / 64, F_ / 64, B_);

    // ===== GAT layer 1 =====
    gemm_kernel<<<dim3(F_ / 64, Rtot / 128), 256, 0, stream>>>(x, W1, nullptr, Wh_buf, Rtot, F_, F_, 0);
    wh12_kernel<<<Rtot / 4, 256, 0, stream>>>(Wh_buf, a1, Wh1v, Wh2v);
    colstats2_kernel<<<statsG, 256, 0, stream>>>(adj, nullptr, mask, Wh1v, Wh2v, pM, pS);
    colfin_kernel<<<finG, 256, 0, stream>>>(pM, pS, Mcol, Sinv);
    transp_kernel<<<trG, 256, 0, stream>>>(Wh_buf, Wht);
    att_mfma_kernel<<<attG, 256, 0, stream>>>(maskB, Wht, Wh1v, Wh2v, Mcol, Sinv, g1out);

    // ===== GAT layer 2 (mask reused, adj not re-read) =====
    gemm_kernel<<<dim3(F_ / 64, Rtot / 128), 256, 0, stream>>>(g1out, W2, nullptr, Wh_buf, Rtot, F_, F_, 0);
    wh12_kernel<<<Rtot / 4, 256, 0, stream>>>(Wh_buf, a2, Wh1v, Wh2v);
    colstats2_kernel<<<statsG, 256, 0, stream>>>(nullptr, mask, nullptr, Wh1v, Wh2v, pM, pS);
    colfin_kernel<<<finG, 256, 0, stream>>>(pM, pS, Mcol, Sinv);
    transp_kernel<<<trG, 256, 0, stream>>>(Wh_buf, Wht);
    att_mfma_kernel<<<attG, 256, 0, stream>>>(maskB, Wht, Wh1v, Wh2v, Mcol, Sinv, g1out);

    // ===== LN1(x + gat2) =====
    addln_kernel<<<Rtot, 256, 0, stream>>>(x, g1out, g_ln1, b_ln1, ln1);

    // ===== FFN (mid overwrites Wht/mask — both dead here) =====
    gemm_kernel<<<dim3(H_ / 64, Rtot / 128), 256, 0, stream>>>(ln1, w_ff1, b_ff1, mid, Rtot, H_, F_, 1);
    gemm_kernel<<<dim3(F_ / 64, Rtot / 128), 256, 0, stream>>>(mid, w_ff2, b_ff2, out, Rtot, F_, H_, 0);

    // ===== LN2(ln1 + ff) =====
    addln_kernel<<<Rtot, 256, 0, stream>>>(ln1, out, g_ln2, b_ln2, out);
}

// Round 3
// 642.180 us; speedup vs baseline: 1.9429x; 1.7564x over previous
//
#include <hip/hip_runtime.h>
#include <math.h>

#define ALPHA 0.2f
#define NEGV  -9e15f
#define EPSV  1e-5f

constexpr int B_ = 2, N_ = 4096, F_ = 256, H_ = 1024;
constexpr int SPLIT_ = 16;   // colstats i-split
constexpr int SPLITJ_ = 4;   // attention j-split

typedef __attribute__((ext_vector_type(4))) float f32x4;
typedef __attribute__((ext_vector_type(8))) short s16x8;

__device__ __forceinline__ unsigned short f2bf(float f) {
    unsigned u = __builtin_bit_cast(unsigned, f);
    u += 0x7fffu + ((u >> 16) & 1u);
    return (unsigned short)(u >> 16);
}

// ---------------- bf16 MFMA GEMM: C[M,Nc] = A[M,K] @ Wt[Nc,K]^T (+bias)(+relu) --
// A fp32 (converted to bf16 in staging), Wt bf16 pre-transposed [Nc][K].
// BM=BN=BK=64, block 256 (4 waves); wave w: i-half (w&1)*32, f-half (w>>1)*32.
__global__ __launch_bounds__(256) void gemm_bf16_kernel(
    const float* __restrict__ A, const unsigned short* __restrict__ Wt,
    const float* __restrict__ bias, float* __restrict__ C,
    int M, int Nc, int K, int relu)
{
    __shared__ unsigned short As[64 * 72];   // [i][k] row stride 72
    __shared__ unsigned short Bs[64 * 72];   // [f][k]
    const int t = threadIdx.x;
    const int w = t >> 6, l = t & 63;
    const int quad = l >> 4, l15 = l & 15;
    const int iw = (w & 1) * 32, fw = (w >> 1) * 32;
    const int row0 = blockIdx.y * 64, col0 = blockIdx.x * 64;

    const int sr = t >> 2;           // 0..63 staged row
    const int sk = (t & 3) * 16;     // k offset (16 k's per thread)

    f32x4 acc[2][2];
    #pragma unroll
    for (int a = 0; a < 2; ++a)
        #pragma unroll
        for (int c = 0; c < 2; ++c) acc[a][c] = (f32x4)(0.f);

    for (int k0 = 0; k0 < K; k0 += 64) {
        // --- stage A (fp32 -> bf16) ---
        {
            const float* ap = &A[(size_t)(row0 + sr) * K + k0 + sk];
            #pragma unroll
            for (int u4 = 0; u4 < 4; ++u4) {
                const float4 v = *(const float4*)&ap[u4 * 4];
                ushort4 o;
                o.x = f2bf(v.x); o.y = f2bf(v.y); o.z = f2bf(v.z); o.w = f2bf(v.w);
                *(ushort4*)&As[sr * 72 + sk + u4 * 4] = o;
            }
        }
        // --- stage B (already bf16) ---
        {
            const unsigned short* bp = &Wt[(size_t)(col0 + sr) * K + k0 + sk];
            *(s16x8*)&Bs[sr * 72 + sk]     = *(const s16x8*)bp;
            *(s16x8*)&Bs[sr * 72 + sk + 8] = *(const s16x8*)(bp + 8);
        }
        __syncthreads();
        #pragma unroll
        for (int ks = 0; ks < 64; ks += 32) {
            s16x8 af[2], bf[2];
            #pragma unroll
            for (int it = 0; it < 2; ++it)
                af[it] = *(const s16x8*)&As[(iw + it * 16 + l15) * 72 + ks + quad * 8];
            #pragma unroll
            for (int ft = 0; ft < 2; ++ft)
                bf[ft] = *(const s16x8*)&Bs[(fw + ft * 16 + l15) * 72 + ks + quad * 8];
            #pragma unroll
            for (int it = 0; it < 2; ++it)
                #pragma unroll
                for (int ft = 0; ft < 2; ++ft)
                    acc[it][ft] = __builtin_amdgcn_mfma_f32_16x16x32_bf16(
                        af[it], bf[ft], acc[it][ft], 0, 0, 0);
        }
        __syncthreads();
    }

    #pragma unroll
    for (int ft = 0; ft < 2; ++ft) {
        const int col = col0 + fw + ft * 16 + l15;
        const float bv = bias ? bias[col] : 0.f;
        #pragma unroll
        for (int it = 0; it < 2; ++it) {
            #pragma unroll
            for (int rr = 0; rr < 4; ++rr) {
                const int row = row0 + iw + it * 16 + quad * 4 + rr;
                float v = acc[it][ft][rr] + bv;
                if (relu) v = fmaxf(v, 0.f);
                C[(size_t)row * Nc + col] = v;
            }
        }
    }
}

// ---------------- Wh1/Wh2 row dots ---------------------------------------------
__global__ __launch_bounds__(256) void wh12_kernel(
    const float* __restrict__ Wh, const float* __restrict__ a,
    float* __restrict__ Wh1, float* __restrict__ Wh2)
{
    const int wid = threadIdx.x >> 6, lane = threadIdx.x & 63;
    const int row = blockIdx.x * 4 + wid;
    const float4 w  = *(const float4*)&Wh[(size_t)row * F_ + lane * 4];
    const float4 u1 = *(const float4*)&a[lane * 4];
    const float4 u2 = *(const float4*)&a[F_ + lane * 4];
    float s1 = w.x * u1.x + w.y * u1.y + w.z * u1.z + w.w * u1.w;
    float s2 = w.x * u2.x + w.y * u2.y + w.z * u2.z + w.w * u2.w;
    #pragma unroll
    for (int off = 32; off > 0; off >>= 1) {
        s1 += __shfl_down(s1, off);
        s2 += __shfl_down(s2, off);
    }
    if (lane == 0) { Wh1[row] = s1; Wh2[row] = s2; }
}

// ---------------- column softmax stats; layer1 reads adj + writes bitmask ------
__global__ __launch_bounds__(256) void colstats2_kernel(
    const int* __restrict__ adj, const unsigned long long* __restrict__ maskIn,
    unsigned long long* __restrict__ maskOut,
    const float* __restrict__ Wh1, const float* __restrict__ Wh2,
    float* __restrict__ pM, float* __restrict__ pS)
{
    const int t = threadIdx.x;
    const int j = blockIdx.x * 256 + t;
    const int sp = blockIdx.y;
    const int b = blockIdx.z;
    const int i0 = sp * (N_ / SPLIT_);
    const int w = t >> 6, lane = t & 63;
    const float w2 = Wh2[b * N_ + j];
    const float* __restrict__ w1p = Wh1 + b * N_ + i0;
    float m = -3.4e38f, s = 0.f;
    for (int ii = 0; ii < N_ / SPLIT_; ++ii) {
        const int i = i0 + ii;
        bool act;
        if (adj) {
            act = adj[((size_t)b * N_ + i) * N_ + j] > 0;
            const unsigned long long bm = __ballot(act);
            if (lane == 0)
                maskOut[((size_t)b * N_ + i) * (N_ / 64) + blockIdx.x * 4 + w] = bm;
        } else {
            const unsigned long long mw =
                maskIn[((size_t)b * N_ + i) * (N_ / 64) + blockIdx.x * 4 + w];
            act = (mw >> (j & 63)) & 1ull;
        }
        float e = w1p[ii] + w2;
        e = fmaxf(e, ALPHA * e);
        const float x = act ? e : NEGV;
        const float nm = fmaxf(m, x);
        s = s * __expf(m - nm) + __expf(x - nm);
        m = nm;
    }
    pM[((size_t)b * SPLIT_ + sp) * N_ + j] = m;
    pS[((size_t)b * SPLIT_ + sp) * N_ + j] = s;
}

__global__ __launch_bounds__(256) void colfin_kernel(
    const float* __restrict__ pM, const float* __restrict__ pS,
    float* __restrict__ Mcol, float* __restrict__ Sinv)
{
    const int j = blockIdx.x * 256 + threadIdx.x;
    const int b = blockIdx.y;
    float m = -3.4e38f;
    #pragma unroll
    for (int s = 0; s < SPLIT_; ++s)
        m = fmaxf(m, pM[((size_t)b * SPLIT_ + s) * N_ + j]);
    float sum = 0.f;
    #pragma unroll
    for (int s = 0; s < SPLIT_; ++s)
        sum += pS[((size_t)b * SPLIT_ + s) * N_ + j] *
               __expf(pM[((size_t)b * SPLIT_ + s) * N_ + j] - m);
    Mcol[b * N_ + j] = m;
    Sinv[b * N_ + j] = 1.0f / sum;
}

// ---------------- transpose + bf16 convert: src[bat][R][Cc] -> dst[bat][Cc][R] --
__global__ __launch_bounds__(256) void transp_kernel(
    const float* __restrict__ src, unsigned short* __restrict__ dst, int R, int Cc)
{
    __shared__ float T[64][65];
    const int t = threadIdx.x;
    const int r0 = blockIdx.x * 64, c0 = blockIdx.y * 64;
    const size_t boff = (size_t)blockIdx.z * R * Cc;
    #pragma unroll
    for (int s = 0; s < 4; ++s) {
        const int rr = s * 16 + (t >> 4);
        const int cq = t & 15;
        const float4 v = *(const float4*)&src[boff + (size_t)(r0 + rr) * Cc + c0 + cq * 4];
        T[rr][cq * 4 + 0] = v.x; T[rr][cq * 4 + 1] = v.y;
        T[rr][cq * 4 + 2] = v.z; T[rr][cq * 4 + 3] = v.w;
    }
    __syncthreads();
    #pragma unroll
    for (int s = 0; s < 4; ++s) {
        const int cr = s * 16 + (t >> 4);
        const int rq = t & 15;
        ushort4 o;
        o.x = f2bf(T[rq * 4 + 0][cr]);
        o.y = f2bf(T[rq * 4 + 1][cr]);
        o.z = f2bf(T[rq * 4 + 2][cr]);
        o.w = f2bf(T[rq * 4 + 3][cr]);
        *(ushort4*)&dst[boff + (size_t)(c0 + cr) * R + r0 + rq * 4] = o;
    }
}

// ---------------- attention matmul, split-j partials ---------------------------
// grid (N/64, SPLITJ, B), block 256 (4 waves). Out tile 64 i x 256 f.
// Wave w owns f-range [w*64, (w+1)*64). 64-j chunks, 2 MFMA k-steps per barrier.
__global__ __launch_bounds__(256) void att_mfma2_kernel(
    const unsigned short* __restrict__ mask16, const unsigned short* __restrict__ Wht,
    const float* __restrict__ Wh1, const float* __restrict__ Wh2,
    const float* __restrict__ Mcol, const float* __restrict__ Sinv,
    float* __restrict__ part)
{
    __shared__ unsigned short Bs[256 * 72];  // [f][j] row stride 72
    __shared__ unsigned short Ps[64 * 72];   // [i][j]

    const int t = threadIdx.x;
    const int w = t >> 6, l = t & 63;
    const int quad = l >> 4, l15 = l & 15;
    const int b = blockIdx.z;
    const int i0 = blockIdx.x * 64;
    const int sp = blockIdx.y;
    const int jbase = sp * (N_ / SPLITJ_);

    const int pi = t >> 2;        // i offset within tile (0..63)
    const int pj4 = t & 3;        // j sub-range pj4*16..+15
    const float w1i = Wh1[b * N_ + i0 + pi];
    const unsigned short* __restrict__ mrow =
        mask16 + ((size_t)b * N_ + i0 + pi) * (N_ / 16);

    f32x4 acc[4][4];
    #pragma unroll
    for (int it = 0; it < 4; ++it)
        #pragma unroll
        for (int ft = 0; ft < 4; ++ft) acc[it][ft] = (f32x4)(0.f);

    const unsigned short* __restrict__ WhtB = Wht + (size_t)b * F_ * N_;
    const float* __restrict__ w2B = Wh2 + b * N_;
    const float* __restrict__ mB  = Mcol + b * N_;
    const float* __restrict__ sB  = Sinv + b * N_;

    for (int itr = 0; itr < (N_ / SPLITJ_) / 64; ++itr) {
        const int jb = jbase + itr * 64;
        // ---- stage B tile: Wh_t[f][jb..jb+63] for all 256 f ----
        #pragma unroll
        for (int s = 0; s < 8; ++s) {
            const int idx = t + s * 256;
            const int f = idx >> 3, prt = idx & 7;
            *(s16x8*)&Bs[f * 72 + prt * 8] =
                *(const s16x8*)&WhtB[(size_t)f * N_ + jb + prt * 8];
        }
        // ---- generate P tile (64 i x 64 j) ----
        {
            const unsigned mb = mrow[jb / 16 + pj4];
            #pragma unroll
            for (int u4 = 0; u4 < 4; ++u4) {
                const int jo = pj4 * 16 + u4 * 4;
                const float4 w2v = *(const float4*)&w2B[jb + jo];
                const float4 mv  = *(const float4*)&mB[jb + jo];
                const float4 sv  = *(const float4*)&sB[jb + jo];
                ushort4 o;
                unsigned short* op = &o.x;
                #pragma unroll
                for (int u = 0; u < 4; ++u) {
                    const float xw = w1i + (&w2v.x)[u];
                    const float e = fmaxf(xw, ALPHA * xw);
                    const float x2 = ((mb >> (u4 * 4 + u)) & 1u) ? e : NEGV;
                    op[u] = f2bf(__expf(x2 - (&mv.x)[u]) * (&sv.x)[u]);
                }
                *(ushort4*)&Ps[pi * 72 + jo] = o;
            }
        }
        __syncthreads();
        // ---- MFMA: 2 k-steps of 32 ----
        #pragma unroll
        for (int ks = 0; ks < 64; ks += 32) {
            s16x8 af[4];
            #pragma unroll
            for (int it = 0; it < 4; ++it)
                af[it] = *(const s16x8*)&Ps[(it * 16 + l15) * 72 + ks + quad * 8];
            #pragma unroll
            for (int ft = 0; ft < 4; ++ft) {
                const s16x8 bf =
                    *(const s16x8*)&Bs[(w * 64 + ft * 16 + l15) * 72 + ks + quad * 8];
                #pragma unroll
                for (int it = 0; it < 4; ++it)
                    acc[it][ft] = __builtin_amdgcn_mfma_f32_16x16x32_bf16(
                        af[it], bf, acc[it][ft], 0, 0, 0);
            }
        }
        __syncthreads();
    }

    // ---- epilogue to fp32 partial [sp][b][i][f] ----
    float* __restrict__ pout = part + ((size_t)sp * B_ + b) * N_ * F_;
    #pragma unroll
    for (int it = 0; it < 4; ++it)
        #pragma unroll
        for (int ft = 0; ft < 4; ++ft) {
            const int col = w * 64 + ft * 16 + l15;
            #pragma unroll
            for (int rr = 0; rr < 4; ++rr) {
                const int row = i0 + it * 16 + quad * 4 + rr;
                pout[(size_t)row * F_ + col] = acc[it][ft][rr];
            }
        }
}

// ---------------- partial reduction (4 splits) ---------------------------------
__global__ __launch_bounds__(256) void reduce4_kernel(
    const float* __restrict__ p, float* __restrict__ out)
{
    const size_t i = ((size_t)blockIdx.x * 256 + threadIdx.x) * 4;
    const size_t S = (size_t)B_ * N_ * F_;
    const float4 a = *(const float4*)&p[i];
    const float4 b = *(const float4*)&p[i + S];
    const float4 c = *(const float4*)&p[i + 2 * S];
    const float4 d = *(const float4*)&p[i + 3 * S];
    float4 o;
    o.x = a.x + b.x + c.x + d.x;
    o.y = a.y + b.y + c.y + d.y;
    o.z = a.z + b.z + c.z + d.z;
    o.w = a.w + b.w + c.w + d.w;
    *(float4*)&out[i] = o;
}

// ---------------- residual add + LayerNorm over F=256 --------------------------
__global__ __launch_bounds__(256) void addln_kernel(
    const float* __restrict__ X, const float* __restrict__ Y,
    const float* __restrict__ g, const float* __restrict__ bta,
    float* __restrict__ out)
{
    const int row = blockIdx.x;
    const int t = threadIdx.x;
    const size_t idx = (size_t)row * F_ + t;
    const float v = X[idx] + Y[idx];
    float s1 = v, s2 = v * v;
    #pragma unroll
    for (int off = 32; off > 0; off >>= 1) {
        s1 += __shfl_down(s1, off);
        s2 += __shfl_down(s2, off);
    }
    __shared__ float r1[4], r2[4];
    __shared__ float mu_s, rs_s;
    const int wid = t >> 6, lane = t & 63;
    if (lane == 0) { r1[wid] = s1; r2[wid] = s2; }
    __syncthreads();
    if (t == 0) {
        const float a = r1[0] + r1[1] + r1[2] + r1[3];
        const float q = r2[0] + r2[1] + r2[2] + r2[3];
        const float mu = a * (1.f / F_);
        const float var = q * (1.f / F_) - mu * mu;
        mu_s = mu;
        rs_s = rsqrtf(var + EPSV);
    }
    __syncthreads();
    out[idx] = (v - mu_s) * rs_s * g[t] + bta[t];
}

// -------------------------------------------------------------------------------
extern "C" void kernel_launch(void* const* d_in, const int* in_sizes, int n_in,
                              void* d_out, int out_size, void* d_ws, size_t ws_size,
                              hipStream_t stream)
{
    const float* x     = (const float*)d_in[0];
    const int*   adj   = (const int*)d_in[1];
    const float* W1    = (const float*)d_in[2];
    const float* a1    = (const float*)d_in[3];
    const float* W2    = (const float*)d_in[4];
    const float* a2    = (const float*)d_in[5];
    const float* w_ff1 = (const float*)d_in[6];
    const float* b_ff1 = (const float*)d_in[7];
    const float* w_ff2 = (const float*)d_in[8];
    const float* b_ff2 = (const float*)d_in[9];
    const float* g_ln1 = (const float*)d_in[10];
    const float* b_ln1 = (const float*)d_in[11];
    const float* g_ln2 = (const float*)d_in[12];
    const float* b_ln2 = (const float*)d_in[13];
    float* out = (float*)d_out;

    const int Rtot = B_ * N_;             // 8192
    float* ws = (float*)d_ws;
    // ---- layout (floats), total 59.9 MB (validated footprint) ----
    float* Wh_buf = ws;                     // 0 .. 2M           (8 MB)
    float* ln1    = ws;                     // alias: after Wh_buf dead
    float* g1out  = ws + 2097152;           // 2M .. 4M          (8 MB)
    float* part   = ws + 4194304;           // 4M .. 12.58M      (32 MB)
    float* mid    = ws + 4194304;           // alias: FFN only (partials dead)
    unsigned short* Wht = (unsigned short*)(ws + 12582912);  // 4 MB
    unsigned short* Wt  = (unsigned short*)(ws + 12582912);  // alias (sequential)
    unsigned long long* mask = (unsigned long long*)(ws + 13631488); // 4 MB
    unsigned short* mask16 = (unsigned short*)mask;
    float* Wh1v = ws + 14680064;
    float* Wh2v = Wh1v + 8192;
    float* Mcol = Wh2v + 8192;
    float* Sinv = Mcol + 8192;
    float* pM   = Sinv + 8192;              // 131072 f
    float* pS   = pM + (size_t)B_ * SPLIT_ * N_;

    const dim3 statsG(N_ / 256, SPLIT_, B_);
    const dim3 finG(N_ / 256, B_);
    const dim3 attG(N_ / 64, SPLITJ_, B_);
    const dim3 trWhG(N_ / 64, F_ / 64, B_);

    // ===== GAT layer 1 =====
    transp_kernel<<<dim3(4, 4, 1), 256, 0, stream>>>(W1, Wt, 256, 256);
    gemm_bf16_kernel<<<dim3(F_ / 64, Rtot / 64), 256, 0, stream>>>(x, Wt, nullptr, Wh_buf, Rtot, F_, F_, 0);
    wh12_kernel<<<Rtot / 4, 256, 0, stream>>>(Wh_buf, a1, Wh1v, Wh2v);
    colstats2_kernel<<<statsG, 256, 0, stream>>>(adj, nullptr, mask, Wh1v, Wh2v, pM, pS);
    colfin_kernel<<<finG, 256, 0, stream>>>(pM, pS, Mcol, Sinv);
    transp_kernel<<<trWhG, 256, 0, stream>>>(Wh_buf, Wht, N_, F_);
    att_mfma2_kernel<<<attG, 256, 0, stream>>>(mask16, Wht, Wh1v, Wh2v, Mcol, Sinv, part);
    reduce4_kernel<<<2048, 256, 0, stream>>>(part, g1out);

    // ===== GAT layer 2 (mask reused; adj read only once per launch) =====
    transp_kernel<<<dim3(4, 4, 1), 256, 0, stream>>>(W2, Wt, 256, 256);
    gemm_bf16_kernel<<<dim3(F_ / 64, Rtot / 64), 256, 0, stream>>>(g1out, Wt, nullptr, Wh_buf, Rtot, F_, F_, 0);
    wh12_kernel<<<Rtot / 4, 256, 0, stream>>>(Wh_buf, a2, Wh1v, Wh2v);
    colstats2_kernel<<<statsG, 256, 0, stream>>>(nullptr, mask, nullptr, Wh1v, Wh2v, pM, pS);
    colfin_kernel<<<finG, 256, 0, stream>>>(pM, pS, Mcol, Sinv);
    transp_kernel<<<trWhG, 256, 0, stream>>>(Wh_buf, Wht, N_, F_);
    att_mfma2_kernel<<<attG, 256, 0, stream>>>(mask16, Wht, Wh1v, Wh2v, Mcol, Sinv, part);
    reduce4_kernel<<<2048, 256, 0, stream>>>(part, g1out);

    // ===== LN1(x + gat2) -> ln1 (aliases Wh_buf; Wh_buf dead) =====
    addln_kernel<<<Rtot, 256, 0, stream>>>(x, g1out, g_ln1, b_ln1, ln1);

    // ===== FFN (mid aliases partials — dead; Wt region free of Wht uses) =====
    transp_kernel<<<dim3(4, 16, 1), 256, 0, stream>>>(w_ff1, Wt, 256, 1024);
    gemm_bf16_kernel<<<dim3(H_ / 64, Rtot / 64), 256, 0, stream>>>(ln1, Wt, b_ff1, mid, Rtot, H_, F_, 1);
    transp_kernel<<<dim3(16, 4, 1), 256, 0, stream>>>(w_ff2, Wt, 1024, 256);
    gemm_bf16_kernel<<<dim3(F_ / 64, Rtot / 64), 256, 0, stream>>>(mid, Wt, b_ff2, out, Rtot, F_, H_, 0);

    // ===== LN2(ln1 + ff) =====
    addln_kernel<<<Rtot, 256, 0, stream>>>(ln1, out, g_ln2, b_ln2, out);
}

// Round 4
// 464.609 us; speedup vs baseline: 2.6854x; 1.3822x over previous
//
#include <hip/hip_runtime.h>
#include <math.h>

#define ALPHA 0.2f
#define NEGV  -9e15f
#define EPSV  1e-5f

constexpr int B_ = 2, N_ = 4096, F_ = 256, H_ = 1024;
constexpr int SPLIT_ = 16;   // colstats i-split
constexpr int SPLITJ_ = 4;   // attention j-split

typedef __attribute__((ext_vector_type(4))) float f32x4;
typedef __attribute__((ext_vector_type(8))) short s16x8;

__device__ __forceinline__ unsigned short f2bf(float f) {
    unsigned u = __builtin_bit_cast(unsigned, f);
    u += 0x7fffu + ((u >> 16) & 1u);
    return (unsigned short)(u >> 16);
}

// ---------------- bf16 MFMA GEMM: C[M,Nc] = A[M,K] @ Wt[Nc,K]^T (+bias)(+relu) --
__global__ __launch_bounds__(256) void gemm_bf16_kernel(
    const float* __restrict__ A, const unsigned short* __restrict__ Wt,
    const float* __restrict__ bias, float* __restrict__ C,
    int M, int Nc, int K, int relu)
{
    __shared__ unsigned short As[64 * 72];
    __shared__ unsigned short Bs[64 * 72];
    const int t = threadIdx.x;
    const int w = t >> 6, l = t & 63;
    const int quad = l >> 4, l15 = l & 15;
    const int iw = (w & 1) * 32, fw = (w >> 1) * 32;
    const int row0 = blockIdx.y * 64, col0 = blockIdx.x * 64;

    const int sr = t >> 2;
    const int sk = (t & 3) * 16;

    f32x4 acc[2][2];
    #pragma unroll
    for (int a = 0; a < 2; ++a)
        #pragma unroll
        for (int c = 0; c < 2; ++c) acc[a][c] = (f32x4)(0.f);

    for (int k0 = 0; k0 < K; k0 += 64) {
        {
            const float* ap = &A[(size_t)(row0 + sr) * K + k0 + sk];
            #pragma unroll
            for (int u4 = 0; u4 < 4; ++u4) {
                const float4 v = *(const float4*)&ap[u4 * 4];
                ushort4 o;
                o.x = f2bf(v.x); o.y = f2bf(v.y); o.z = f2bf(v.z); o.w = f2bf(v.w);
                *(ushort4*)&As[sr * 72 + sk + u4 * 4] = o;
            }
        }
        {
            const unsigned short* bp = &Wt[(size_t)(col0 + sr) * K + k0 + sk];
            *(s16x8*)&Bs[sr * 72 + sk]     = *(const s16x8*)bp;
            *(s16x8*)&Bs[sr * 72 + sk + 8] = *(const s16x8*)(bp + 8);
        }
        __syncthreads();
        #pragma unroll
        for (int ks = 0; ks < 64; ks += 32) {
            s16x8 af[2], bf[2];
            #pragma unroll
            for (int it = 0; it < 2; ++it)
                af[it] = *(const s16x8*)&As[(iw + it * 16 + l15) * 72 + ks + quad * 8];
            #pragma unroll
            for (int ft = 0; ft < 2; ++ft)
                bf[ft] = *(const s16x8*)&Bs[(fw + ft * 16 + l15) * 72 + ks + quad * 8];
            #pragma unroll
            for (int it = 0; it < 2; ++it)
                #pragma unroll
                for (int ft = 0; ft < 2; ++ft)
                    acc[it][ft] = __builtin_amdgcn_mfma_f32_16x16x32_bf16(
                        af[it], bf[ft], acc[it][ft], 0, 0, 0);
        }
        __syncthreads();
    }

    #pragma unroll
    for (int ft = 0; ft < 2; ++ft) {
        const int col = col0 + fw + ft * 16 + l15;
        const float bv = bias ? bias[col] : 0.f;
        #pragma unroll
        for (int it = 0; it < 2; ++it) {
            #pragma unroll
            for (int rr = 0; rr < 4; ++rr) {
                const int row = row0 + iw + it * 16 + quad * 4 + rr;
                float v = acc[it][ft][rr] + bv;
                if (relu) v = fmaxf(v, 0.f);
                C[(size_t)row * Nc + col] = v;
            }
        }
    }
}

// ---------------- Wh1/Wh2 row dots ---------------------------------------------
__global__ __launch_bounds__(256) void wh12_kernel(
    const float* __restrict__ Wh, const float* __restrict__ a,
    float* __restrict__ Wh1, float* __restrict__ Wh2)
{
    const int wid = threadIdx.x >> 6, lane = threadIdx.x & 63;
    const int row = blockIdx.x * 4 + wid;
    const float4 w  = *(const float4*)&Wh[(size_t)row * F_ + lane * 4];
    const float4 u1 = *(const float4*)&a[lane * 4];
    const float4 u2 = *(const float4*)&a[F_ + lane * 4];
    float s1 = w.x * u1.x + w.y * u1.y + w.z * u1.z + w.w * u1.w;
    float s2 = w.x * u2.x + w.y * u2.y + w.z * u2.z + w.w * u2.w;
    #pragma unroll
    for (int off = 32; off > 0; off >>= 1) {
        s1 += __shfl_down(s1, off);
        s2 += __shfl_down(s2, off);
    }
    if (lane == 0) { Wh1[row] = s1; Wh2[row] = s2; }
}

// ---------------- pure-streaming adj -> bitmask pack ---------------------------
// Linear bit-pack: bit (L & 63) of word (L >> 6), L = (b*N + i)*N + j.
__global__ __launch_bounds__(256) void maskpack_kernel(
    const int* __restrict__ adj, unsigned long long* __restrict__ mask)
{
    const int t = threadIdx.x;
    const int w = t >> 6, l = t & 63;
    const int wid = blockIdx.x * 4 + w;
    const int nw = gridDim.x * 4;
    const int nchunks = (B_ * N_ * N_) / 256;     // 256 elements per wave-chunk
    for (int c = wid; c < nchunks; c += nw) {
        const size_t base = (size_t)c * 256;
        #pragma unroll
        for (int r = 0; r < 4; ++r) {
            const int v = adj[base + r * 64 + l];
            const unsigned long long bm = __ballot(v > 0);
            if (l == 0) mask[base / 64 + r] = bm;
        }
    }
}

// ---------------- column softmax stats from bitmask (both layers) --------------
// grid (N/256, SPLIT, B), block 256; thread = column j; i in chunks of 8 (ILP).
__global__ __launch_bounds__(256) void colstats3_kernel(
    const unsigned long long* __restrict__ mask,
    const float* __restrict__ Wh1, const float* __restrict__ Wh2,
    float* __restrict__ pM, float* __restrict__ pS)
{
    const int t = threadIdx.x;
    const int j = blockIdx.x * 256 + t;
    const int sp = blockIdx.y;
    const int b = blockIdx.z;
    const int i0 = sp * (N_ / SPLIT_);
    const int w = t >> 6;
    const int jbit = t & 63;
    const float w2 = Wh2[b * N_ + j];
    const unsigned long long* __restrict__ mbase =
        mask + ((size_t)b * N_ + i0) * (N_ / 64) + blockIdx.x * 4 + w;
    const float* __restrict__ w1p = Wh1 + b * N_ + i0;

    float m = -3.4e38f, s = 0.f;
    for (int c = 0; c < N_ / SPLIT_; c += 8) {
        float x[8];
        #pragma unroll
        for (int u = 0; u < 8; ++u) {
            const unsigned long long mw = mbase[(size_t)(c + u) * (N_ / 64)];
            const float e0 = w1p[c + u] + w2;
            const float e = fmaxf(e0, ALPHA * e0);
            x[u] = ((mw >> jbit) & 1ull) ? e : NEGV;
        }
        float cm = fmaxf(fmaxf(fmaxf(x[0], x[1]), fmaxf(x[2], x[3])),
                         fmaxf(fmaxf(x[4], x[5]), fmaxf(x[6], x[7])));
        const float nm = fmaxf(m, cm);
        float cs = 0.f;
        #pragma unroll
        for (int u = 0; u < 8; ++u) cs += __expf(x[u] - nm);
        s = s * __expf(m - nm) + cs;
        m = nm;
    }
    pM[((size_t)b * SPLIT_ + sp) * N_ + j] = m;
    pS[((size_t)b * SPLIT_ + sp) * N_ + j] = s;
}

__global__ __launch_bounds__(256) void colfin_kernel(
    const float* __restrict__ pM, const float* __restrict__ pS,
    float* __restrict__ Mcol, float* __restrict__ Sinv)
{
    const int j = blockIdx.x * 256 + threadIdx.x;
    const int b = blockIdx.y;
    float m = -3.4e38f;
    #pragma unroll
    for (int s = 0; s < SPLIT_; ++s)
        m = fmaxf(m, pM[((size_t)b * SPLIT_ + s) * N_ + j]);
    float sum = 0.f;
    #pragma unroll
    for (int s = 0; s < SPLIT_; ++s)
        sum += pS[((size_t)b * SPLIT_ + s) * N_ + j] *
               __expf(pM[((size_t)b * SPLIT_ + s) * N_ + j] - m);
    Mcol[b * N_ + j] = m;
    Sinv[b * N_ + j] = 1.0f / sum;
}

// ---------------- transpose + bf16 convert: src[bat][R][Cc] -> dst[bat][Cc][R] --
__global__ __launch_bounds__(256) void transp_kernel(
    const float* __restrict__ src, unsigned short* __restrict__ dst, int R, int Cc)
{
    __shared__ float T[64][65];
    const int t = threadIdx.x;
    const int r0 = blockIdx.x * 64, c0 = blockIdx.y * 64;
    const size_t boff = (size_t)blockIdx.z * R * Cc;
    #pragma unroll
    for (int s = 0; s < 4; ++s) {
        const int rr = s * 16 + (t >> 4);
        const int cq = t & 15;
        const float4 v = *(const float4*)&src[boff + (size_t)(r0 + rr) * Cc + c0 + cq * 4];
        T[rr][cq * 4 + 0] = v.x; T[rr][cq * 4 + 1] = v.y;
        T[rr][cq * 4 + 2] = v.z; T[rr][cq * 4 + 3] = v.w;
    }
    __syncthreads();
    #pragma unroll
    for (int s = 0; s < 4; ++s) {
        const int cr = s * 16 + (t >> 4);
        const int rq = t & 15;
        ushort4 o;
        o.x = f2bf(T[rq * 4 + 0][cr]);
        o.y = f2bf(T[rq * 4 + 1][cr]);
        o.z = f2bf(T[rq * 4 + 2][cr]);
        o.w = f2bf(T[rq * 4 + 3][cr]);
        *(ushort4*)&dst[boff + (size_t)(c0 + cr) * R + r0 + rq * 4] = o;
    }
}

// ---------------- attention matmul, split-j partials ---------------------------
__global__ __launch_bounds__(256) void att_mfma2_kernel(
    const unsigned short* __restrict__ mask16, const unsigned short* __restrict__ Wht,
    const float* __restrict__ Wh1, const float* __restrict__ Wh2,
    const float* __restrict__ Mcol, const float* __restrict__ Sinv,
    float* __restrict__ part)
{
    __shared__ unsigned short Bs[256 * 72];
    __shared__ unsigned short Ps[64 * 72];

    const int t = threadIdx.x;
    const int w = t >> 6, l = t & 63;
    const int quad = l >> 4, l15 = l & 15;
    const int b = blockIdx.z;
    const int i0 = blockIdx.x * 64;
    const int sp = blockIdx.y;
    const int jbase = sp * (N_ / SPLITJ_);

    const int pi = t >> 2;
    const int pj4 = t & 3;
    const float w1i = Wh1[b * N_ + i0 + pi];
    const unsigned short* __restrict__ mrow =
        mask16 + ((size_t)b * N_ + i0 + pi) * (N_ / 16);

    f32x4 acc[4][4];
    #pragma unroll
    for (int it = 0; it < 4; ++it)
        #pragma unroll
        for (int ft = 0; ft < 4; ++ft) acc[it][ft] = (f32x4)(0.f);

    const unsigned short* __restrict__ WhtB = Wht + (size_t)b * F_ * N_;
    const float* __restrict__ w2B = Wh2 + b * N_;
    const float* __restrict__ mB  = Mcol + b * N_;
    const float* __restrict__ sB  = Sinv + b * N_;

    for (int itr = 0; itr < (N_ / SPLITJ_) / 64; ++itr) {
        const int jb = jbase + itr * 64;
        #pragma unroll
        for (int s = 0; s < 8; ++s) {
            const int idx = t + s * 256;
            const int f = idx >> 3, prt = idx & 7;
            *(s16x8*)&Bs[f * 72 + prt * 8] =
                *(const s16x8*)&WhtB[(size_t)f * N_ + jb + prt * 8];
        }
        {
            const unsigned mb = mrow[jb / 16 + pj4];
            #pragma unroll
            for (int u4 = 0; u4 < 4; ++u4) {
                const int jo = pj4 * 16 + u4 * 4;
                const float4 w2v = *(const float4*)&w2B[jb + jo];
                const float4 mv  = *(const float4*)&mB[jb + jo];
                const float4 sv  = *(const float4*)&sB[jb + jo];
                ushort4 o;
                unsigned short* op = &o.x;
                #pragma unroll
                for (int u = 0; u < 4; ++u) {
                    const float xw = w1i + (&w2v.x)[u];
                    const float e = fmaxf(xw, ALPHA * xw);
                    const float x2 = ((mb >> (u4 * 4 + u)) & 1u) ? e : NEGV;
                    op[u] = f2bf(__expf(x2 - (&mv.x)[u]) * (&sv.x)[u]);
                }
                *(ushort4*)&Ps[pi * 72 + jo] = o;
            }
        }
        __syncthreads();
        #pragma unroll
        for (int ks = 0; ks < 64; ks += 32) {
            s16x8 af[4];
            #pragma unroll
            for (int it = 0; it < 4; ++it)
                af[it] = *(const s16x8*)&Ps[(it * 16 + l15) * 72 + ks + quad * 8];
            #pragma unroll
            for (int ft = 0; ft < 4; ++ft) {
                const s16x8 bf =
                    *(const s16x8*)&Bs[(w * 64 + ft * 16 + l15) * 72 + ks + quad * 8];
                #pragma unroll
                for (int it = 0; it < 4; ++it)
                    acc[it][ft] = __builtin_amdgcn_mfma_f32_16x16x32_bf16(
                        af[it], bf, acc[it][ft], 0, 0, 0);
            }
        }
        __syncthreads();
    }

    float* __restrict__ pout = part + ((size_t)sp * B_ + b) * N_ * F_;
    #pragma unroll
    for (int it = 0; it < 4; ++it)
        #pragma unroll
        for (int ft = 0; ft < 4; ++ft) {
            const int col = w * 64 + ft * 16 + l15;
            #pragma unroll
            for (int rr = 0; rr < 4; ++rr) {
                const int row = i0 + it * 16 + quad * 4 + rr;
                pout[(size_t)row * F_ + col] = acc[it][ft][rr];
            }
        }
}

// ---------------- partial reduction (4 splits) ---------------------------------
__global__ __launch_bounds__(256) void reduce4_kernel(
    const float* __restrict__ p, float* __restrict__ out)
{
    const size_t i = ((size_t)blockIdx.x * 256 + threadIdx.x) * 4;
    const size_t S = (size_t)B_ * N_ * F_;
    const float4 a = *(const float4*)&p[i];
    const float4 b = *(const float4*)&p[i + S];
    const float4 c = *(const float4*)&p[i + 2 * S];
    const float4 d = *(const float4*)&p[i + 3 * S];
    float4 o;
    o.x = a.x + b.x + c.x + d.x;
    o.y = a.y + b.y + c.y + d.y;
    o.z = a.z + b.z + c.z + d.z;
    o.w = a.w + b.w + c.w + d.w;
    *(float4*)&out[i] = o;
}

// ---------------- residual add + LayerNorm over F=256 --------------------------
__global__ __launch_bounds__(256) void addln_kernel(
    const float* __restrict__ X, const float* __restrict__ Y,
    const float* __restrict__ g, const float* __restrict__ bta,
    float* __restrict__ out)
{
    const int row = blockIdx.x;
    const int t = threadIdx.x;
    const size_t idx = (size_t)row * F_ + t;
    const float v = X[idx] + Y[idx];
    float s1 = v, s2 = v * v;
    #pragma unroll
    for (int off = 32; off > 0; off >>= 1) {
        s1 += __shfl_down(s1, off);
        s2 += __shfl_down(s2, off);
    }
    __shared__ float r1[4], r2[4];
    __shared__ float mu_s, rs_s;
    const int wid = t >> 6, lane = t & 63;
    if (lane == 0) { r1[wid] = s1; r2[wid] = s2; }
    __syncthreads();
    if (t == 0) {
        const float a = r1[0] + r1[1] + r1[2] + r1[3];
        const float q = r2[0] + r2[1] + r2[2] + r2[3];
        const float mu = a * (1.f / F_);
        const float var = q * (1.f / F_) - mu * mu;
        mu_s = mu;
        rs_s = rsqrtf(var + EPSV);
    }
    __syncthreads();
    out[idx] = (v - mu_s) * rs_s * g[t] + bta[t];
}

// -------------------------------------------------------------------------------
extern "C" void kernel_launch(void* const* d_in, const int* in_sizes, int n_in,
                              void* d_out, int out_size, void* d_ws, size_t ws_size,
                              hipStream_t stream)
{
    const float* x     = (const float*)d_in[0];
    const int*   adj   = (const int*)d_in[1];
    const float* W1    = (const float*)d_in[2];
    const float* a1    = (const float*)d_in[3];
    const float* W2    = (const float*)d_in[4];
    const float* a2    = (const float*)d_in[5];
    const float* w_ff1 = (const float*)d_in[6];
    const float* b_ff1 = (const float*)d_in[7];
    const float* w_ff2 = (const float*)d_in[8];
    const float* b_ff2 = (const float*)d_in[9];
    const float* g_ln1 = (const float*)d_in[10];
    const float* b_ln1 = (const float*)d_in[11];
    const float* g_ln2 = (const float*)d_in[12];
    const float* b_ln2 = (const float*)d_in[13];
    float* out = (float*)d_out;

    const int Rtot = B_ * N_;             // 8192
    float* ws = (float*)d_ws;
    float* Wh_buf = ws;                     // 0 .. 2M           (8 MB)
    float* ln1    = ws;                     // alias: after Wh_buf dead
    float* g1out  = ws + 2097152;           // 2M .. 4M          (8 MB)
    float* part   = ws + 4194304;           // 4M .. 12.58M      (32 MB)
    float* mid    = ws + 4194304;           // alias: FFN only
    unsigned short* Wht = (unsigned short*)(ws + 12582912);  // 4 MB
    unsigned short* Wt  = (unsigned short*)(ws + 12582912);  // alias (sequential)
    unsigned long long* mask = (unsigned long long*)(ws + 13631488); // 4 MB
    unsigned short* mask16 = (unsigned short*)mask;
    float* Wh1v = ws + 14680064;
    float* Wh2v = Wh1v + 8192;
    float* Mcol = Wh2v + 8192;
    float* Sinv = Mcol + 8192;
    float* pM   = Sinv + 8192;              // 131072 f
    float* pS   = pM + (size_t)B_ * SPLIT_ * N_;

    const dim3 statsG(N_ / 256, SPLIT_, B_);
    const dim3 finG(N_ / 256, B_);
    const dim3 attG(N_ / 64, SPLITJ_, B_);
    const dim3 trWhG(N_ / 64, F_ / 64, B_);

    // ===== adj -> bitmask (once; streaming) =====
    maskpack_kernel<<<2048, 256, 0, stream>>>(adj, mask);

    // ===== GAT layer 1 =====
    transp_kernel<<<dim3(4, 4, 1), 256, 0, stream>>>(W1, Wt, 256, 256);
    gemm_bf16_kernel<<<dim3(F_ / 64, Rtot / 64), 256, 0, stream>>>(x, Wt, nullptr, Wh_buf, Rtot, F_, F_, 0);
    wh12_kernel<<<Rtot / 4, 256, 0, stream>>>(Wh_buf, a1, Wh1v, Wh2v);
    colstats3_kernel<<<statsG, 256, 0, stream>>>(mask, Wh1v, Wh2v, pM, pS);
    colfin_kernel<<<finG, 256, 0, stream>>>(pM, pS, Mcol, Sinv);
    transp_kernel<<<trWhG, 256, 0, stream>>>(Wh_buf, Wht, N_, F_);
    att_mfma2_kernel<<<attG, 256, 0, stream>>>(mask16, Wht, Wh1v, Wh2v, Mcol, Sinv, part);
    reduce4_kernel<<<2048, 256, 0, stream>>>(part, g1out);

    // ===== GAT layer 2 =====
    transp_kernel<<<dim3(4, 4, 1), 256, 0, stream>>>(W2, Wt, 256, 256);
    gemm_bf16_kernel<<<dim3(F_ / 64, Rtot / 64), 256, 0, stream>>>(g1out, Wt, nullptr, Wh_buf, Rtot, F_, F_, 0);
    wh12_kernel<<<Rtot / 4, 256, 0, stream>>>(Wh_buf, a2, Wh1v, Wh2v);
    colstats3_kernel<<<statsG, 256, 0, stream>>>(mask, Wh1v, Wh2v, pM, pS);
    colfin_kernel<<<finG, 256, 0, stream>>>(pM, pS, Mcol, Sinv);
    transp_kernel<<<trWhG, 256, 0, stream>>>(Wh_buf, Wht, N_, F_);
    att_mfma2_kernel<<<attG, 256, 0, stream>>>(mask16, Wht, Wh1v, Wh2v, Mcol, Sinv, part);
    reduce4_kernel<<<2048, 256, 0, stream>>>(part, g1out);

    // ===== LN1(x + gat2) =====
    addln_kernel<<<Rtot, 256, 0, stream>>>(x, g1out, g_ln1, b_ln1, ln1);

    // ===== FFN =====
    transp_kernel<<<dim3(4, 16, 1), 256, 0, stream>>>(w_ff1, Wt, 256, 1024);
    gemm_bf16_kernel<<<dim3(H_ / 64, Rtot / 64), 256, 0, stream>>>(ln1, Wt, b_ff1, mid, Rtot, H_, F_, 1);
    transp_kernel<<<dim3(16, 4, 1), 256, 0, stream>>>(w_ff2, Wt, 1024, 256);
    gemm_bf16_kernel<<<dim3(F_ / 64, Rtot / 64), 256, 0, stream>>>(mid, Wt, b_ff2, out, Rtot, F_, H_, 0);

    // ===== LN2(ln1 + ff) =====
    addln_kernel<<<Rtot, 256, 0, stream>>>(ln1, out, g_ln2, b_ln2, out);
}

// Round 5
// 423.961 us; speedup vs baseline: 2.9429x; 1.0959x over previous
//
#include <hip/hip_runtime.h>
#include <math.h>

#define ALPHA 0.2f
#define NEGV  -9e15f
#define EPSV  1e-5f

constexpr int B_ = 2, N_ = 4096, F_ = 256, H_ = 1024;
constexpr int SPLIT_ = 16;   // colstats i-split
constexpr int SPLITJ_ = 4;   // attention j-split

typedef __attribute__((ext_vector_type(4))) float f32x4;
typedef __attribute__((ext_vector_type(8))) short s16x8;

__device__ __forceinline__ unsigned short f2bf(float f) {
    unsigned u = __builtin_bit_cast(unsigned, f);
    u += 0x7fffu + ((u >> 16) & 1u);
    return (unsigned short)(u >> 16);
}

// ---------------- bf16 MFMA GEMM with optional fused transposed-bf16 output ----
// C[M,Nc] = A[M,K] @ Wt[Nc,K]^T (+bias)(+relu). A fp32 or bf16; C fp32 or bf16.
// Tout (optional): bf16 [b][col][i] (N_-row batched) written from the acc tile.
__global__ __launch_bounds__(256) void gemm2_kernel(
    const void* __restrict__ Ap, const unsigned short* __restrict__ Wt,
    const float* __restrict__ bias, void* __restrict__ Cp,
    unsigned short* __restrict__ Tout,
    int M, int Nc, int K, int relu, int a_bf16, int c_bf16)
{
    __shared__ unsigned short As[64 * 72];
    __shared__ unsigned short Bs[64 * 72];
    const int t = threadIdx.x;
    const int w = t >> 6, l = t & 63;
    const int quad = l >> 4, l15 = l & 15;
    const int iw = (w & 1) * 32, fw = (w >> 1) * 32;
    const int row0 = blockIdx.y * 64, col0 = blockIdx.x * 64;

    const int sr = t >> 2;
    const int sk = (t & 3) * 16;

    f32x4 acc[2][2];
    #pragma unroll
    for (int a = 0; a < 2; ++a)
        #pragma unroll
        for (int c = 0; c < 2; ++c) acc[a][c] = (f32x4)(0.f);

    for (int k0 = 0; k0 < K; k0 += 64) {
        if (a_bf16) {
            const unsigned short* ap =
                (const unsigned short*)Ap + (size_t)(row0 + sr) * K + k0 + sk;
            *(s16x8*)&As[sr * 72 + sk]     = *(const s16x8*)ap;
            *(s16x8*)&As[sr * 72 + sk + 8] = *(const s16x8*)(ap + 8);
        } else {
            const float* ap = (const float*)Ap + (size_t)(row0 + sr) * K + k0 + sk;
            #pragma unroll
            for (int u4 = 0; u4 < 4; ++u4) {
                const float4 v = *(const float4*)&ap[u4 * 4];
                ushort4 o;
                o.x = f2bf(v.x); o.y = f2bf(v.y); o.z = f2bf(v.z); o.w = f2bf(v.w);
                *(ushort4*)&As[sr * 72 + sk + u4 * 4] = o;
            }
        }
        {
            const unsigned short* bp = &Wt[(size_t)(col0 + sr) * K + k0 + sk];
            *(s16x8*)&Bs[sr * 72 + sk]     = *(const s16x8*)bp;
            *(s16x8*)&Bs[sr * 72 + sk + 8] = *(const s16x8*)(bp + 8);
        }
        __syncthreads();
        #pragma unroll
        for (int ks = 0; ks < 64; ks += 32) {
            s16x8 af[2], bf[2];
            #pragma unroll
            for (int it = 0; it < 2; ++it)
                af[it] = *(const s16x8*)&As[(iw + it * 16 + l15) * 72 + ks + quad * 8];
            #pragma unroll
            for (int ft = 0; ft < 2; ++ft)
                bf[ft] = *(const s16x8*)&Bs[(fw + ft * 16 + l15) * 72 + ks + quad * 8];
            #pragma unroll
            for (int it = 0; it < 2; ++it)
                #pragma unroll
                for (int ft = 0; ft < 2; ++ft)
                    acc[it][ft] = __builtin_amdgcn_mfma_f32_16x16x32_bf16(
                        af[it], bf[ft], acc[it][ft], 0, 0, 0);
        }
        __syncthreads();
    }

    #pragma unroll
    for (int ft = 0; ft < 2; ++ft) {
        const int col = col0 + fw + ft * 16 + l15;
        const float bv = bias ? bias[col] : 0.f;
        #pragma unroll
        for (int it = 0; it < 2; ++it) {
            float v0 = acc[it][ft][0] + bv, v1 = acc[it][ft][1] + bv;
            float v2 = acc[it][ft][2] + bv, v3 = acc[it][ft][3] + bv;
            if (relu) {
                v0 = fmaxf(v0, 0.f); v1 = fmaxf(v1, 0.f);
                v2 = fmaxf(v2, 0.f); v3 = fmaxf(v3, 0.f);
            }
            const int rbase = row0 + iw + it * 16 + quad * 4;
            if (c_bf16) {
                unsigned short* Cs = (unsigned short*)Cp;
                Cs[(size_t)(rbase + 0) * Nc + col] = f2bf(v0);
                Cs[(size_t)(rbase + 1) * Nc + col] = f2bf(v1);
                Cs[(size_t)(rbase + 2) * Nc + col] = f2bf(v2);
                Cs[(size_t)(rbase + 3) * Nc + col] = f2bf(v3);
            } else {
                float* Cf = (float*)Cp;
                Cf[(size_t)(rbase + 0) * Nc + col] = v0;
                Cf[(size_t)(rbase + 1) * Nc + col] = v1;
                Cf[(size_t)(rbase + 2) * Nc + col] = v2;
                Cf[(size_t)(rbase + 3) * Nc + col] = v3;
            }
            if (Tout) {
                const int bb = row0 >> 12;               // N_ = 4096
                const int ibase = (row0 & (N_ - 1)) + iw + it * 16 + quad * 4;
                ushort4 o;
                o.x = f2bf(acc[it][ft][0]); o.y = f2bf(acc[it][ft][1]);
                o.z = f2bf(acc[it][ft][2]); o.w = f2bf(acc[it][ft][3]);
                *(ushort4*)&Tout[((size_t)bb * F_ + col) * N_ + ibase] = o;
            }
        }
    }
}

// ---------------- Wh1/Wh2 row dots ---------------------------------------------
__global__ __launch_bounds__(256) void wh12_kernel(
    const float* __restrict__ Wh, const float* __restrict__ a,
    float* __restrict__ Wh1, float* __restrict__ Wh2)
{
    const int wid = threadIdx.x >> 6, lane = threadIdx.x & 63;
    const int row = blockIdx.x * 4 + wid;
    const float4 w  = *(const float4*)&Wh[(size_t)row * F_ + lane * 4];
    const float4 u1 = *(const float4*)&a[lane * 4];
    const float4 u2 = *(const float4*)&a[F_ + lane * 4];
    float s1 = w.x * u1.x + w.y * u1.y + w.z * u1.z + w.w * u1.w;
    float s2 = w.x * u2.x + w.y * u2.y + w.z * u2.z + w.w * u2.w;
    #pragma unroll
    for (int off = 32; off > 0; off >>= 1) {
        s1 += __shfl_down(s1, off);
        s2 += __shfl_down(s2, off);
    }
    if (lane == 0) { Wh1[row] = s1; Wh2[row] = s2; }
}

// ---------------- layer-1: adj -> stats + bitmask (fused, 8-wide ILP) ----------
__global__ __launch_bounds__(256) void colstats_adj_kernel(
    const int* __restrict__ adj, unsigned long long* __restrict__ maskOut,
    const float* __restrict__ Wh1, const float* __restrict__ Wh2,
    float* __restrict__ pM, float* __restrict__ pS)
{
    const int t = threadIdx.x;
    const int j = blockIdx.x * 256 + t;
    const int sp = blockIdx.y;
    const int b = blockIdx.z;
    const int i0 = sp * (N_ / SPLIT_);
    const int w = t >> 6, l = t & 63;
    const float w2 = Wh2[b * N_ + j];
    const float* __restrict__ w1p = Wh1 + b * N_ + i0;
    const int* __restrict__ ap = adj + ((size_t)b * N_ + i0) * N_ + j;

    float m = -3.4e38f, s = 0.f;
    for (int c = 0; c < N_ / SPLIT_; c += 8) {
        int v[8];
        #pragma unroll
        for (int u = 0; u < 8; ++u) v[u] = ap[(size_t)(c + u) * N_];
        float x[8];
        #pragma unroll
        for (int u = 0; u < 8; ++u) {
            const bool act = v[u] > 0;
            const unsigned long long bm = __ballot(act);
            if (l == 0)
                maskOut[((size_t)b * N_ + i0 + c + u) * (N_ / 64) + blockIdx.x * 4 + w] = bm;
            const float e0 = w1p[c + u] + w2;
            const float e = fmaxf(e0, ALPHA * e0);
            x[u] = act ? e : NEGV;
        }
        const float cm = fmaxf(fmaxf(fmaxf(x[0], x[1]), fmaxf(x[2], x[3])),
                               fmaxf(fmaxf(x[4], x[5]), fmaxf(x[6], x[7])));
        const float nm = fmaxf(m, cm);
        float cs = 0.f;
        #pragma unroll
        for (int u = 0; u < 8; ++u) cs += __expf(x[u] - nm);
        s = s * __expf(m - nm) + cs;
        m = nm;
    }
    pM[((size_t)b * SPLIT_ + sp) * N_ + j] = m;
    pS[((size_t)b * SPLIT_ + sp) * N_ + j] = s;
}

// ---------------- layer-2: stats from bitmask ----------------------------------
__global__ __launch_bounds__(256) void colstats3_kernel(
    const unsigned long long* __restrict__ mask,
    const float* __restrict__ Wh1, const float* __restrict__ Wh2,
    float* __restrict__ pM, float* __restrict__ pS)
{
    const int t = threadIdx.x;
    const int j = blockIdx.x * 256 + t;
    const int sp = blockIdx.y;
    const int b = blockIdx.z;
    const int i0 = sp * (N_ / SPLIT_);
    const int w = t >> 6;
    const int jbit = t & 63;
    const float w2 = Wh2[b * N_ + j];
    const unsigned long long* __restrict__ mbase =
        mask + ((size_t)b * N_ + i0) * (N_ / 64) + blockIdx.x * 4 + w;
    const float* __restrict__ w1p = Wh1 + b * N_ + i0;

    float m = -3.4e38f, s = 0.f;
    for (int c = 0; c < N_ / SPLIT_; c += 8) {
        float x[8];
        #pragma unroll
        for (int u = 0; u < 8; ++u) {
            const unsigned long long mw = mbase[(size_t)(c + u) * (N_ / 64)];
            const float e0 = w1p[c + u] + w2;
            const float e = fmaxf(e0, ALPHA * e0);
            x[u] = ((mw >> jbit) & 1ull) ? e : NEGV;
        }
        const float cm = fmaxf(fmaxf(fmaxf(x[0], x[1]), fmaxf(x[2], x[3])),
                               fmaxf(fmaxf(x[4], x[5]), fmaxf(x[6], x[7])));
        const float nm = fmaxf(m, cm);
        float cs = 0.f;
        #pragma unroll
        for (int u = 0; u < 8; ++u) cs += __expf(x[u] - nm);
        s = s * __expf(m - nm) + cs;
        m = nm;
    }
    pM[((size_t)b * SPLIT_ + sp) * N_ + j] = m;
    pS[((size_t)b * SPLIT_ + sp) * N_ + j] = s;
}

// ---------------- finalize: mo = m + ln(sum); P = exp(x - mo) ------------------
__global__ __launch_bounds__(256) void colfin2_kernel(
    const float* __restrict__ pM, const float* __restrict__ pS,
    float* __restrict__ Mo)
{
    const int j = blockIdx.x * 256 + threadIdx.x;
    const int b = blockIdx.y;
    float m = -3.4e38f;
    #pragma unroll
    for (int s = 0; s < SPLIT_; ++s)
        m = fmaxf(m, pM[((size_t)b * SPLIT_ + s) * N_ + j]);
    float sum = 0.f;
    #pragma unroll
    for (int s = 0; s < SPLIT_; ++s)
        sum += pS[((size_t)b * SPLIT_ + s) * N_ + j] *
               __expf(pM[((size_t)b * SPLIT_ + s) * N_ + j] - m);
    Mo[b * N_ + j] = m + logf(sum);
}

// ---------------- transpose + bf16 convert (weights): src[R][Cc] -> dst[Cc][R] --
__global__ __launch_bounds__(256) void transp_kernel(
    const float* __restrict__ src, unsigned short* __restrict__ dst, int R, int Cc)
{
    __shared__ float T[64][65];
    const int t = threadIdx.x;
    const int r0 = blockIdx.x * 64, c0 = blockIdx.y * 64;
    #pragma unroll
    for (int s = 0; s < 4; ++s) {
        const int rr = s * 16 + (t >> 4);
        const int cq = t & 15;
        const float4 v = *(const float4*)&src[(size_t)(r0 + rr) * Cc + c0 + cq * 4];
        T[rr][cq * 4 + 0] = v.x; T[rr][cq * 4 + 1] = v.y;
        T[rr][cq * 4 + 2] = v.z; T[rr][cq * 4 + 3] = v.w;
    }
    __syncthreads();
    #pragma unroll
    for (int s = 0; s < 4; ++s) {
        const int cr = s * 16 + (t >> 4);
        const int rq = t & 15;
        ushort4 o;
        o.x = f2bf(T[rq * 4 + 0][cr]);
        o.y = f2bf(T[rq * 4 + 1][cr]);
        o.z = f2bf(T[rq * 4 + 2][cr]);
        o.w = f2bf(T[rq * 4 + 3][cr]);
        *(ushort4*)&dst[(size_t)(c0 + cr) * R + r0 + rq * 4] = o;
    }
}

// ---------------- attention matmul, pipelined, split-j partials ----------------
__global__ __launch_bounds__(256) void att_mfma3_kernel(
    const unsigned short* __restrict__ mask16, const unsigned short* __restrict__ Wht,
    const float* __restrict__ Wh1, const float* __restrict__ Wh2,
    const float* __restrict__ Mo, float* __restrict__ part)
{
    __shared__ unsigned short Bs[256 * 72];
    __shared__ unsigned short Ps[64 * 72];
    __shared__ float w2s[1024];
    __shared__ float mos[1024];

    const int t = threadIdx.x;
    const int w = t >> 6, l = t & 63;
    const int quad = l >> 4, l15 = l & 15;
    const int b = blockIdx.z;
    const int i0 = blockIdx.x * 64;
    const int sp = blockIdx.y;
    const int jbase = sp * (N_ / SPLITJ_);

    const int pi = t >> 2;
    const int pj4 = t & 3;
    const float w1i = Wh1[b * N_ + i0 + pi];
    const unsigned short* __restrict__ mrow =
        mask16 + ((size_t)b * N_ + i0 + pi) * (N_ / 16);
    const unsigned short* __restrict__ WhtB = Wht + (size_t)b * F_ * N_;

    // one-time per-block stats preload (j-range = 1024)
    {
        const float4 a = *(const float4*)&Wh2[b * N_ + jbase + t * 4];
        const float4 c = *(const float4*)&Mo[b * N_ + jbase + t * 4];
        *(float4*)&w2s[t * 4] = a;
        *(float4*)&mos[t * 4] = c;
    }

    f32x4 acc[4][4];
    #pragma unroll
    for (int it = 0; it < 4; ++it)
        #pragma unroll
        for (int ft = 0; ft < 4; ++ft) acc[it][ft] = (f32x4)(0.f);

    const int f0s = t >> 3;
    const int prt = (t & 7) * 8;
    s16x8 breg[8];
    // prefetch iter-0 B tile + mask
    {
        const int jb = jbase;
        #pragma unroll
        for (int s = 0; s < 8; ++s)
            breg[s] = *(const s16x8*)&WhtB[(size_t)(f0s + s * 32) * N_ + jb + prt];
    }
    unsigned short mb_cur = mrow[jbase / 16 + pj4];
    __syncthreads();   // stats LDS ready

    constexpr int NITER = (N_ / SPLITJ_) / 64;
    for (int itr = 0; itr < NITER; ++itr) {
        const int jb = jbase + itr * 64;
        // ---- write B tile from prefetched regs ----
        #pragma unroll
        for (int s = 0; s < 8; ++s)
            *(s16x8*)&Bs[(f0s + s * 32) * 72 + prt] = breg[s];
        // ---- P gen (stats from LDS) ----
        {
            const unsigned mb = mb_cur;
            const int jl = itr * 64 + pj4 * 16;
            #pragma unroll
            for (int u4 = 0; u4 < 4; ++u4) {
                const float4 w2v = *(const float4*)&w2s[jl + u4 * 4];
                const float4 mov = *(const float4*)&mos[jl + u4 * 4];
                ushort4 o;
                unsigned short* op = &o.x;
                #pragma unroll
                for (int u = 0; u < 4; ++u) {
                    const float xw = w1i + (&w2v.x)[u];
                    const float e = fmaxf(xw, ALPHA * xw);
                    const float x2 = ((mb >> (u4 * 4 + u)) & 1u) ? e : NEGV;
                    op[u] = f2bf(__expf(x2 - (&mov.x)[u]));
                }
                *(ushort4*)&Ps[pi * 72 + pj4 * 16 + u4 * 4] = o;
            }
        }
        __syncthreads();
        // ---- prefetch next iter (overlaps MFMA phase) ----
        if (itr + 1 < NITER) {
            const int jn = jb + 64;
            #pragma unroll
            for (int s = 0; s < 8; ++s)
                breg[s] = *(const s16x8*)&WhtB[(size_t)(f0s + s * 32) * N_ + jn + prt];
            mb_cur = mrow[jn / 16 + pj4];
        }
        // ---- MFMA ----
        #pragma unroll
        for (int ks = 0; ks < 64; ks += 32) {
            s16x8 af[4];
            #pragma unroll
            for (int it = 0; it < 4; ++it)
                af[it] = *(const s16x8*)&Ps[(it * 16 + l15) * 72 + ks + quad * 8];
            #pragma unroll
            for (int ft = 0; ft < 4; ++ft) {
                const s16x8 bf =
                    *(const s16x8*)&Bs[(w * 64 + ft * 16 + l15) * 72 + ks + quad * 8];
                #pragma unroll
                for (int it = 0; it < 4; ++it)
                    acc[it][ft] = __builtin_amdgcn_mfma_f32_16x16x32_bf16(
                        af[it], bf, acc[it][ft], 0, 0, 0);
            }
        }
        __syncthreads();
    }

    float* __restrict__ pout = part + ((size_t)sp * B_ + b) * N_ * F_;
    #pragma unroll
    for (int it = 0; it < 4; ++it)
        #pragma unroll
        for (int ft = 0; ft < 4; ++ft) {
            const int col = w * 64 + ft * 16 + l15;
            #pragma unroll
            for (int rr = 0; rr < 4; ++rr) {
                const int row = i0 + it * 16 + quad * 4 + rr;
                pout[(size_t)row * F_ + col] = acc[it][ft][rr];
            }
        }
}

// ---------------- partial reduction (4 splits) ---------------------------------
__global__ __launch_bounds__(256) void reduce4_kernel(
    const float* __restrict__ p, float* __restrict__ out)
{
    const size_t i = ((size_t)blockIdx.x * 256 + threadIdx.x) * 4;
    const size_t S = (size_t)B_ * N_ * F_;
    const float4 a = *(const float4*)&p[i];
    const float4 b = *(const float4*)&p[i + S];
    const float4 c = *(const float4*)&p[i + 2 * S];
    const float4 d = *(const float4*)&p[i + 3 * S];
    float4 o;
    o.x = a.x + b.x + c.x + d.x;
    o.y = a.y + b.y + c.y + d.y;
    o.z = a.z + b.z + c.z + d.z;
    o.w = a.w + b.w + c.w + d.w;
    *(float4*)&out[i] = o;
}

// ---------------- residual add + LayerNorm over F=256 --------------------------
__global__ __launch_bounds__(256) void addln_kernel(
    const float* __restrict__ X, const float* __restrict__ Y,
    const float* __restrict__ g, const float* __restrict__ bta,
    float* __restrict__ out)
{
    const int row = blockIdx.x;
    const int t = threadIdx.x;
    const size_t idx = (size_t)row * F_ + t;
    const float v = X[idx] + Y[idx];
    float s1 = v, s2 = v * v;
    #pragma unroll
    for (int off = 32; off > 0; off >>= 1) {
        s1 += __shfl_down(s1, off);
        s2 += __shfl_down(s2, off);
    }
    __shared__ float r1[4], r2[4];
    __shared__ float mu_s, rs_s;
    const int wid = t >> 6, lane = t & 63;
    if (lane == 0) { r1[wid] = s1; r2[wid] = s2; }
    __syncthreads();
    if (t == 0) {
        const float a = r1[0] + r1[1] + r1[2] + r1[3];
        const float q = r2[0] + r2[1] + r2[2] + r2[3];
        const float mu = a * (1.f / F_);
        const float var = q * (1.f / F_) - mu * mu;
        mu_s = mu;
        rs_s = rsqrtf(var + EPSV);
    }
    __syncthreads();
    out[idx] = (v - mu_s) * rs_s * g[t] + bta[t];
}

// -------------------------------------------------------------------------------
extern "C" void kernel_launch(void* const* d_in, const int* in_sizes, int n_in,
                              void* d_out, int out_size, void* d_ws, size_t ws_size,
                              hipStream_t stream)
{
    const float* x     = (const float*)d_in[0];
    const int*   adj   = (const int*)d_in[1];
    const float* W1    = (const float*)d_in[2];
    const float* a1    = (const float*)d_in[3];
    const float* W2    = (const float*)d_in[4];
    const float* a2    = (const float*)d_in[5];
    const float* w_ff1 = (const float*)d_in[6];
    const float* b_ff1 = (const float*)d_in[7];
    const float* w_ff2 = (const float*)d_in[8];
    const float* b_ff2 = (const float*)d_in[9];
    const float* g_ln1 = (const float*)d_in[10];
    const float* b_ln1 = (const float*)d_in[11];
    const float* g_ln2 = (const float*)d_in[12];
    const float* b_ln2 = (const float*)d_in[13];
    float* out = (float*)d_out;

    const int Rtot = B_ * N_;             // 8192
    float* ws = (float*)d_ws;
    // ---- de-aliased layout (ws is 512 MiB; ~86 MB used) ----
    float* Wh_buf = ws;                                   // [0, 2M)
    float* g1out  = ws + 2097152;                         // [2M, 4M)
    float* ln1    = ws + 4194304;                         // [4M, 6M)
    float* part   = ws + 6291456;                         // [6M, 14M) 4 splits
    unsigned short* mid_us = (unsigned short*)(ws + 14680064);   // 8M bf16
    unsigned short* Wht    = (unsigned short*)(ws + 18874368);   // 2M bf16
    unsigned long long* mask = (unsigned long long*)(ws + 19922944); // 4 MB
    unsigned short* mask16 = (unsigned short*)mask;
    float* Wh1v = ws + 20971520;
    float* Wh2v = Wh1v + 8192;
    float* Mo   = Wh2v + 8192;
    float* pM   = Mo + 8192;                              // 131072
    float* pS   = pM + (size_t)B_ * SPLIT_ * N_;          // 131072
    unsigned short* Wt = (unsigned short*)(ws + 21299200); // 512 KB max

    const dim3 statsG(N_ / 256, SPLIT_, B_);
    const dim3 finG(N_ / 256, B_);
    const dim3 attG(N_ / 64, SPLITJ_, B_);

    // ===== GAT layer 1 =====
    transp_kernel<<<dim3(4, 4), 256, 0, stream>>>(W1, Wt, 256, 256);
    gemm2_kernel<<<dim3(F_ / 64, Rtot / 64), 256, 0, stream>>>(
        x, Wt, nullptr, Wh_buf, Wht, Rtot, F_, F_, 0, 0, 0);
    wh12_kernel<<<Rtot / 4, 256, 0, stream>>>(Wh_buf, a1, Wh1v, Wh2v);
    colstats_adj_kernel<<<statsG, 256, 0, stream>>>(adj, mask, Wh1v, Wh2v, pM, pS);
    colfin2_kernel<<<finG, 256, 0, stream>>>(pM, pS, Mo);
    att_mfma3_kernel<<<attG, 256, 0, stream>>>(mask16, Wht, Wh1v, Wh2v, Mo, part);
    reduce4_kernel<<<2048, 256, 0, stream>>>(part, g1out);

    // ===== GAT layer 2 (mask reused from layer 1) =====
    transp_kernel<<<dim3(4, 4), 256, 0, stream>>>(W2, Wt, 256, 256);
    gemm2_kernel<<<dim3(F_ / 64, Rtot / 64), 256, 0, stream>>>(
        g1out, Wt, nullptr, Wh_buf, Wht, Rtot, F_, F_, 0, 0, 0);
    wh12_kernel<<<Rtot / 4, 256, 0, stream>>>(Wh_buf, a2, Wh1v, Wh2v);
    colstats3_kernel<<<statsG, 256, 0, stream>>>(mask, Wh1v, Wh2v, pM, pS);
    colfin2_kernel<<<finG, 256, 0, stream>>>(pM, pS, Mo);
    att_mfma3_kernel<<<attG, 256, 0, stream>>>(mask16, Wht, Wh1v, Wh2v, Mo, part);
    reduce4_kernel<<<2048, 256, 0, stream>>>(part, g1out);

    // ===== LN1(x + gat2) =====
    addln_kernel<<<Rtot, 256, 0, stream>>>(x, g1out, g_ln1, b_ln1, ln1);

    // ===== FFN (mid in bf16) =====
    transp_kernel<<<dim3(4, 16), 256, 0, stream>>>(w_ff1, Wt, 256, 1024);
    gemm2_kernel<<<dim3(H_ / 64, Rtot / 64), 256, 0, stream>>>(
        ln1, Wt, b_ff1, mid_us, nullptr, Rtot, H_, F_, 1, 0, 1);
    transp_kernel<<<dim3(16, 4), 256, 0, stream>>>(w_ff2, Wt, 1024, 256);
    gemm2_kernel<<<dim3(F_ / 64, Rtot / 64), 256, 0, stream>>>(
        mid_us, Wt, b_ff2, out, nullptr, Rtot, F_, H_, 0, 1, 0);

    // ===== LN2(ln1 + ff) =====
    addln_kernel<<<Rtot, 256, 0, stream>>>(ln1, out, g_ln2, b_ln2, out);
}

// Round 6
// 423.559 us; speedup vs baseline: 2.9457x; 1.0010x over previous
//
#include <hip/hip_runtime.h>
#include <math.h>

#define ALPHA 0.2f
#define NEGV  -9e15f
#define EPSV  1e-5f

constexpr int B_ = 2, N_ = 4096, F_ = 256, H_ = 1024;
constexpr int SPLIT_ = 16;   // colstats i-split
constexpr int SPLITJ_ = 4;   // attention j-split

typedef __attribute__((ext_vector_type(4))) float f32x4;
typedef __attribute__((ext_vector_type(8))) short s16x8;

__device__ __forceinline__ unsigned short f2bf(float f) {
    unsigned u = __builtin_bit_cast(unsigned, f);
    u += 0x7fffu + ((u >> 16) & 1u);
    return (unsigned short)(u >> 16);
}

// ---------------- zero scratch for Wh1/Wh2 atomics -----------------------------
__global__ __launch_bounds__(256) void zero_kernel(float* __restrict__ p)
{
    const int i = (blockIdx.x * 256 + threadIdx.x) * 4;
    *(float4*)&p[i] = make_float4(0.f, 0.f, 0.f, 0.f);
}

// ---------------- batched weight transpose + bf16: src[R][C] -> dst[C][R] ------
__global__ __launch_bounds__(256) void transp_all_kernel(
    const float* __restrict__ W1, const float* __restrict__ W2,
    const float* __restrict__ F1s, const float* __restrict__ F2s,
    unsigned short* __restrict__ D1, unsigned short* __restrict__ D2,
    unsigned short* __restrict__ D3, unsigned short* __restrict__ D4)
{
    const int mi = blockIdx.z;
    const float* src; unsigned short* dst; int R, Cc;
    if (mi == 0)      { src = W1;  dst = D1; R = 256;  Cc = 256; }
    else if (mi == 1) { src = W2;  dst = D2; R = 256;  Cc = 256; }
    else if (mi == 2) { src = F1s; dst = D3; R = 256;  Cc = 1024; }
    else              { src = F2s; dst = D4; R = 1024; Cc = 256; }
    const int r0 = blockIdx.x * 64, c0 = blockIdx.y * 64;
    if (r0 >= R || c0 >= Cc) return;

    __shared__ float T[64][65];
    const int t = threadIdx.x;
    #pragma unroll
    for (int s = 0; s < 4; ++s) {
        const int rr = s * 16 + (t >> 4);
        const int cq = t & 15;
        const float4 v = *(const float4*)&src[(size_t)(r0 + rr) * Cc + c0 + cq * 4];
        T[rr][cq * 4 + 0] = v.x; T[rr][cq * 4 + 1] = v.y;
        T[rr][cq * 4 + 2] = v.z; T[rr][cq * 4 + 3] = v.w;
    }
    __syncthreads();
    #pragma unroll
    for (int s = 0; s < 4; ++s) {
        const int cr = s * 16 + (t >> 4);
        const int rq = t & 15;
        ushort4 o;
        o.x = f2bf(T[rq * 4 + 0][cr]);
        o.y = f2bf(T[rq * 4 + 1][cr]);
        o.z = f2bf(T[rq * 4 + 2][cr]);
        o.w = f2bf(T[rq * 4 + 3][cr]);
        *(ushort4*)&dst[(size_t)(c0 + cr) * R + r0 + rq * 4] = o;
    }
}

// ---------------- 128x128 bf16 MFMA GEMM (M fixed 8192) ------------------------
// C[8192,Nc] = A[8192,K] @ Wt[Nc,K]^T. c_mode: 0 none, 1 fp32, 2 bf16.
// Tout (opt): bf16 [b][col][i] transposed (no bias). wha (opt): fused row-dots
// Wh1[row] += sum_col acc*wha[col], Wh2 += sum_col acc*wha[F_+col] (atomics).
__global__ __launch_bounds__(256) void gemm128_kernel(
    const void* __restrict__ Ap, const unsigned short* __restrict__ Wt,
    const float* __restrict__ bias, void* __restrict__ Cp,
    unsigned short* __restrict__ Tout, const float* __restrict__ wha,
    float* __restrict__ Wh1, float* __restrict__ Wh2,
    int Nc, int K, int relu, int a_bf16, int c_mode)
{
    __shared__ unsigned short As[128 * 72];
    __shared__ unsigned short Bs[128 * 72];
    const int t = threadIdx.x;
    const int w = t >> 6, l = t & 63;
    const int quad = l >> 4, l15 = l & 15;
    const int wr = w & 1, wc = w >> 1;
    const int row0 = blockIdx.y * 128, col0 = blockIdx.x * 128;
    const int sr = t >> 1;           // 0..127
    const int sk = (t & 1) * 32;     // 0 or 32

    f32x4 acc[4][4];
    #pragma unroll
    for (int it = 0; it < 4; ++it)
        #pragma unroll
        for (int ft = 0; ft < 4; ++ft) acc[it][ft] = (f32x4)(0.f);

    for (int k0 = 0; k0 < K; k0 += 64) {
        if (a_bf16) {
            const unsigned short* ap =
                (const unsigned short*)Ap + (size_t)(row0 + sr) * K + k0 + sk;
            #pragma unroll
            for (int u = 0; u < 4; ++u)
                *(s16x8*)&As[sr * 72 + sk + u * 8] = *(const s16x8*)(ap + u * 8);
        } else {
            const float* ap = (const float*)Ap + (size_t)(row0 + sr) * K + k0 + sk;
            #pragma unroll
            for (int u = 0; u < 8; ++u) {
                const float4 v = *(const float4*)(ap + u * 4);
                ushort4 o;
                o.x = f2bf(v.x); o.y = f2bf(v.y); o.z = f2bf(v.z); o.w = f2bf(v.w);
                *(ushort4*)&As[sr * 72 + sk + u * 4] = o;
            }
        }
        {
            const unsigned short* bp = Wt + (size_t)(col0 + sr) * K + k0 + sk;
            #pragma unroll
            for (int u = 0; u < 4; ++u)
                *(s16x8*)&Bs[sr * 72 + sk + u * 8] = *(const s16x8*)(bp + u * 8);
        }
        __syncthreads();
        #pragma unroll
        for (int ks = 0; ks < 64; ks += 32) {
            s16x8 af[4], bf[4];
            #pragma unroll
            for (int it = 0; it < 4; ++it)
                af[it] = *(const s16x8*)&As[(wr * 64 + it * 16 + l15) * 72 + ks + quad * 8];
            #pragma unroll
            for (int ft = 0; ft < 4; ++ft)
                bf[ft] = *(const s16x8*)&Bs[(wc * 64 + ft * 16 + l15) * 72 + ks + quad * 8];
            #pragma unroll
            for (int ft = 0; ft < 4; ++ft)
                #pragma unroll
                for (int it = 0; it < 4; ++it)
                    acc[it][ft] = __builtin_amdgcn_mfma_f32_16x16x32_bf16(
                        af[it], bf[ft], acc[it][ft], 0, 0, 0);
        }
        __syncthreads();
    }

    if (c_mode) {
        #pragma unroll
        for (int ft = 0; ft < 4; ++ft) {
            const int col = col0 + wc * 64 + ft * 16 + l15;
            const float bv = bias ? bias[col] : 0.f;
            #pragma unroll
            for (int it = 0; it < 4; ++it) {
                const int rbase = row0 + wr * 64 + it * 16 + quad * 4;
                #pragma unroll
                for (int rr = 0; rr < 4; ++rr) {
                    float v = acc[it][ft][rr] + bv;
                    if (relu) v = fmaxf(v, 0.f);
                    if (c_mode == 2)
                        ((unsigned short*)Cp)[(size_t)(rbase + rr) * Nc + col] = f2bf(v);
                    else
                        ((float*)Cp)[(size_t)(rbase + rr) * Nc + col] = v;
                }
            }
        }
    }

    if (Tout) {
        const int bb = row0 >> 12;
        #pragma unroll
        for (int ft = 0; ft < 4; ++ft) {
            const int col = col0 + wc * 64 + ft * 16 + l15;
            #pragma unroll
            for (int it = 0; it < 4; ++it) {
                const int ibase = (row0 & (N_ - 1)) + wr * 64 + it * 16 + quad * 4;
                ushort4 o;
                o.x = f2bf(acc[it][ft][0]); o.y = f2bf(acc[it][ft][1]);
                o.z = f2bf(acc[it][ft][2]); o.w = f2bf(acc[it][ft][3]);
                *(ushort4*)&Tout[((size_t)bb * F_ + col) * N_ + ibase] = o;
            }
        }
    }

    if (wha) {
        float a1v[4], a2v[4];
        #pragma unroll
        for (int ft = 0; ft < 4; ++ft) {
            const int col = col0 + wc * 64 + ft * 16 + l15;
            a1v[ft] = wha[col];
            a2v[ft] = wha[F_ + col];
        }
        #pragma unroll
        for (int it = 0; it < 4; ++it)
            #pragma unroll
            for (int rr = 0; rr < 4; ++rr) {
                float s1 = 0.f, s2 = 0.f;
                #pragma unroll
                for (int ft = 0; ft < 4; ++ft) {
                    s1 += acc[it][ft][rr] * a1v[ft];
                    s2 += acc[it][ft][rr] * a2v[ft];
                }
                #pragma unroll
                for (int mkk = 1; mkk < 16; mkk <<= 1) {
                    s1 += __shfl_xor(s1, mkk);
                    s2 += __shfl_xor(s2, mkk);
                }
                if (l15 == 0) {
                    const int row = row0 + wr * 64 + it * 16 + quad * 4 + rr;
                    atomicAdd(&Wh1[row], s1);
                    atomicAdd(&Wh2[row], s2);
                }
            }
    }
}

// ---------------- layer-1: adj -> stats + bitmask (fused, 8-wide ILP) ----------
__global__ __launch_bounds__(256) void colstats_adj_kernel(
    const int* __restrict__ adj, unsigned long long* __restrict__ maskOut,
    const float* __restrict__ Wh1, const float* __restrict__ Wh2,
    float* __restrict__ pM, float* __restrict__ pS)
{
    const int t = threadIdx.x;
    const int j = blockIdx.x * 256 + t;
    const int sp = blockIdx.y;
    const int b = blockIdx.z;
    const int i0 = sp * (N_ / SPLIT_);
    const int w = t >> 6, l = t & 63;
    const float w2 = Wh2[b * N_ + j];
    const float* __restrict__ w1p = Wh1 + b * N_ + i0;
    const int* __restrict__ ap = adj + ((size_t)b * N_ + i0) * N_ + j;

    float m = -3.4e38f, s = 0.f;
    for (int c = 0; c < N_ / SPLIT_; c += 8) {
        int v[8];
        #pragma unroll
        for (int u = 0; u < 8; ++u) v[u] = ap[(size_t)(c + u) * N_];
        float x[8];
        #pragma unroll
        for (int u = 0; u < 8; ++u) {
            const bool act = v[u] > 0;
            const unsigned long long bm = __ballot(act);
            if (l == 0)
                maskOut[((size_t)b * N_ + i0 + c + u) * (N_ / 64) + blockIdx.x * 4 + w] = bm;
            const float e0 = w1p[c + u] + w2;
            const float e = fmaxf(e0, ALPHA * e0);
            x[u] = act ? e : NEGV;
        }
        const float cm = fmaxf(fmaxf(fmaxf(x[0], x[1]), fmaxf(x[2], x[3])),
                               fmaxf(fmaxf(x[4], x[5]), fmaxf(x[6], x[7])));
        const float nm = fmaxf(m, cm);
        float cs = 0.f;
        #pragma unroll
        for (int u = 0; u < 8; ++u) cs += __expf(x[u] - nm);
        s = s * __expf(m - nm) + cs;
        m = nm;
    }
    pM[((size_t)b * SPLIT_ + sp) * N_ + j] = m;
    pS[((size_t)b * SPLIT_ + sp) * N_ + j] = s;
}

// ---------------- layer-2: stats from bitmask ----------------------------------
__global__ __launch_bounds__(256) void colstats3_kernel(
    const unsigned long long* __restrict__ mask,
    const float* __restrict__ Wh1, const float* __restrict__ Wh2,
    float* __restrict__ pM, float* __restrict__ pS)
{
    const int t = threadIdx.x;
    const int j = blockIdx.x * 256 + t;
    const int sp = blockIdx.y;
    const int b = blockIdx.z;
    const int i0 = sp * (N_ / SPLIT_);
    const int w = t >> 6;
    const int jbit = t & 63;
    const float w2 = Wh2[b * N_ + j];
    const unsigned long long* __restrict__ mbase =
        mask + ((size_t)b * N_ + i0) * (N_ / 64) + blockIdx.x * 4 + w;
    const float* __restrict__ w1p = Wh1 + b * N_ + i0;

    float m = -3.4e38f, s = 0.f;
    for (int c = 0; c < N_ / SPLIT_; c += 8) {
        float x[8];
        #pragma unroll
        for (int u = 0; u < 8; ++u) {
            const unsigned long long mw = mbase[(size_t)(c + u) * (N_ / 64)];
            const float e0 = w1p[c + u] + w2;
            const float e = fmaxf(e0, ALPHA * e0);
            x[u] = ((mw >> jbit) & 1ull) ? e : NEGV;
        }
        const float cm = fmaxf(fmaxf(fmaxf(x[0], x[1]), fmaxf(x[2], x[3])),
                               fmaxf(fmaxf(x[4], x[5]), fmaxf(x[6], x[7])));
        const float nm = fmaxf(m, cm);
        float cs = 0.f;
        #pragma unroll
        for (int u = 0; u < 8; ++u) cs += __expf(x[u] - nm);
        s = s * __expf(m - nm) + cs;
        m = nm;
    }
    pM[((size_t)b * SPLIT_ + sp) * N_ + j] = m;
    pS[((size_t)b * SPLIT_ + sp) * N_ + j] = s;
}

// ---------------- finalize: mo = m + ln(sum) -----------------------------------
__global__ __launch_bounds__(256) void colfin2_kernel(
    const float* __restrict__ pM, const float* __restrict__ pS,
    float* __restrict__ Mo)
{
    const int j = blockIdx.x * 256 + threadIdx.x;
    const int b = blockIdx.y;
    float m = -3.4e38f;
    #pragma unroll
    for (int s = 0; s < SPLIT_; ++s)
        m = fmaxf(m, pM[((size_t)b * SPLIT_ + s) * N_ + j]);
    float sum = 0.f;
    #pragma unroll
    for (int s = 0; s < SPLIT_; ++s)
        sum += pS[((size_t)b * SPLIT_ + s) * N_ + j] *
               __expf(pM[((size_t)b * SPLIT_ + s) * N_ + j] - m);
    Mo[b * N_ + j] = m + logf(sum);
}

// ---------------- attention matmul, pipelined, split-j partials ----------------
__global__ __launch_bounds__(256) void att_mfma3_kernel(
    const unsigned short* __restrict__ mask16, const unsigned short* __restrict__ Wht,
    const float* __restrict__ Wh1, const float* __restrict__ Wh2,
    const float* __restrict__ Mo, float* __restrict__ part)
{
    __shared__ unsigned short Bs[256 * 72];
    __shared__ unsigned short Ps[64 * 72];
    __shared__ float w2s[1024];
    __shared__ float mos[1024];

    const int t = threadIdx.x;
    const int w = t >> 6, l = t & 63;
    const int quad = l >> 4, l15 = l & 15;
    const int b = blockIdx.z;
    const int i0 = blockIdx.x * 64;
    const int sp = blockIdx.y;
    const int jbase = sp * (N_ / SPLITJ_);

    const int pi = t >> 2;
    const int pj4 = t & 3;
    const float w1i = Wh1[b * N_ + i0 + pi];
    const unsigned short* __restrict__ mrow =
        mask16 + ((size_t)b * N_ + i0 + pi) * (N_ / 16);
    const unsigned short* __restrict__ WhtB = Wht + (size_t)b * F_ * N_;

    {
        const float4 a = *(const float4*)&Wh2[b * N_ + jbase + t * 4];
        const float4 c = *(const float4*)&Mo[b * N_ + jbase + t * 4];
        *(float4*)&w2s[t * 4] = a;
        *(float4*)&mos[t * 4] = c;
    }

    f32x4 acc[4][4];
    #pragma unroll
    for (int it = 0; it < 4; ++it)
        #pragma unroll
        for (int ft = 0; ft < 4; ++ft) acc[it][ft] = (f32x4)(0.f);

    const int f0s = t >> 3;
    const int prt = (t & 7) * 8;
    s16x8 breg[8];
    {
        const int jb = jbase;
        #pragma unroll
        for (int s = 0; s < 8; ++s)
            breg[s] = *(const s16x8*)&WhtB[(size_t)(f0s + s * 32) * N_ + jb + prt];
    }
    unsigned short mb_cur = mrow[jbase / 16 + pj4];
    __syncthreads();

    constexpr int NITER = (N_ / SPLITJ_) / 64;
    for (int itr = 0; itr < NITER; ++itr) {
        const int jb = jbase + itr * 64;
        #pragma unroll
        for (int s = 0; s < 8; ++s)
            *(s16x8*)&Bs[(f0s + s * 32) * 72 + prt] = breg[s];
        {
            const unsigned mb = mb_cur;
            const int jl = itr * 64 + pj4 * 16;
            #pragma unroll
            for (int u4 = 0; u4 < 4; ++u4) {
                const float4 w2v = *(const float4*)&w2s[jl + u4 * 4];
                const float4 mov = *(const float4*)&mos[jl + u4 * 4];
                ushort4 o;
                unsigned short* op = &o.x;
                #pragma unroll
                for (int u = 0; u < 4; ++u) {
                    const float xw = w1i + (&w2v.x)[u];
                    const float e = fmaxf(xw, ALPHA * xw);
                    const float x2 = ((mb >> (u4 * 4 + u)) & 1u) ? e : NEGV;
                    op[u] = f2bf(__expf(x2 - (&mov.x)[u]));
                }
                *(ushort4*)&Ps[pi * 72 + pj4 * 16 + u4 * 4] = o;
            }
        }
        __syncthreads();
        if (itr + 1 < NITER) {
            const int jn = jb + 64;
            #pragma unroll
            for (int s = 0; s < 8; ++s)
                breg[s] = *(const s16x8*)&WhtB[(size_t)(f0s + s * 32) * N_ + jn + prt];
            mb_cur = mrow[jn / 16 + pj4];
        }
        #pragma unroll
        for (int ks = 0; ks < 64; ks += 32) {
            s16x8 af[4];
            #pragma unroll
            for (int it = 0; it < 4; ++it)
                af[it] = *(const s16x8*)&Ps[(it * 16 + l15) * 72 + ks + quad * 8];
            #pragma unroll
            for (int ft = 0; ft < 4; ++ft) {
                const s16x8 bf =
                    *(const s16x8*)&Bs[(w * 64 + ft * 16 + l15) * 72 + ks + quad * 8];
                #pragma unroll
                for (int it = 0; it < 4; ++it)
                    acc[it][ft] = __builtin_amdgcn_mfma_f32_16x16x32_bf16(
                        af[it], bf, acc[it][ft], 0, 0, 0);
            }
        }
        __syncthreads();
    }

    float* __restrict__ pout = part + ((size_t)sp * B_ + b) * N_ * F_;
    #pragma unroll
    for (int it = 0; it < 4; ++it)
        #pragma unroll
        for (int ft = 0; ft < 4; ++ft) {
            const int col = w * 64 + ft * 16 + l15;
            #pragma unroll
            for (int rr = 0; rr < 4; ++rr) {
                const int row = i0 + it * 16 + quad * 4 + rr;
                pout[(size_t)row * F_ + col] = acc[it][ft][rr];
            }
        }
}

// ---------------- partial reduction (4 splits) -> bf16 [row][f] ----------------
__global__ __launch_bounds__(256) void reduce4b_kernel(
    const float* __restrict__ p, unsigned short* __restrict__ outb)
{
    const size_t i = ((size_t)blockIdx.x * 256 + threadIdx.x) * 4;
    const size_t S = (size_t)B_ * N_ * F_;
    const float4 a = *(const float4*)&p[i];
    const float4 b = *(const float4*)&p[i + S];
    const float4 c = *(const float4*)&p[i + 2 * S];
    const float4 d = *(const float4*)&p[i + 3 * S];
    ushort4 o;
    o.x = f2bf(a.x + b.x + c.x + d.x);
    o.y = f2bf(a.y + b.y + c.y + d.y);
    o.z = f2bf(a.z + b.z + c.z + d.z);
    o.w = f2bf(a.w + b.w + c.w + d.w);
    *(ushort4*)&outb[i] = o;
}

// ---------------- x + 4-way partial sum + LayerNorm -> fp32 + bf16 -------------
__global__ __launch_bounds__(256) void addln4_kernel(
    const float* __restrict__ X, const float* __restrict__ p,
    const float* __restrict__ g, const float* __restrict__ bta,
    float* __restrict__ outf, unsigned short* __restrict__ outb)
{
    const int row = blockIdx.x;
    const int t = threadIdx.x;
    const size_t idx = (size_t)row * F_ + t;
    const size_t S = (size_t)B_ * N_ * F_;
    const float v = X[idx] + p[idx] + p[idx + S] + p[idx + 2 * S] + p[idx + 3 * S];
    float s1 = v, s2 = v * v;
    #pragma unroll
    for (int off = 32; off > 0; off >>= 1) {
        s1 += __shfl_down(s1, off);
        s2 += __shfl_down(s2, off);
    }
    __shared__ float r1[4], r2[4];
    __shared__ float mu_s, rs_s;
    const int wid = t >> 6, lane = t & 63;
    if (lane == 0) { r1[wid] = s1; r2[wid] = s2; }
    __syncthreads();
    if (t == 0) {
        const float a = r1[0] + r1[1] + r1[2] + r1[3];
        const float q = r2[0] + r2[1] + r2[2] + r2[3];
        const float mu = a * (1.f / F_);
        const float var = q * (1.f / F_) - mu * mu;
        mu_s = mu;
        rs_s = rsqrtf(var + EPSV);
    }
    __syncthreads();
    const float r = (v - mu_s) * rs_s * g[t] + bta[t];
    outf[idx] = r;
    outb[idx] = f2bf(r);
}

// ---------------- residual add + LayerNorm (final) -----------------------------
__global__ __launch_bounds__(256) void addln_kernel(
    const float* __restrict__ X, const float* __restrict__ Y,
    const float* __restrict__ g, const float* __restrict__ bta,
    float* __restrict__ out)
{
    const int row = blockIdx.x;
    const int t = threadIdx.x;
    const size_t idx = (size_t)row * F_ + t;
    const float v = X[idx] + Y[idx];
    float s1 = v, s2 = v * v;
    #pragma unroll
    for (int off = 32; off > 0; off >>= 1) {
        s1 += __shfl_down(s1, off);
        s2 += __shfl_down(s2, off);
    }
    __shared__ float r1[4], r2[4];
    __shared__ float mu_s, rs_s;
    const int wid = t >> 6, lane = t & 63;
    if (lane == 0) { r1[wid] = s1; r2[wid] = s2; }
    __syncthreads();
    if (t == 0) {
        const float a = r1[0] + r1[1] + r1[2] + r1[3];
        const float q = r2[0] + r2[1] + r2[2] + r2[3];
        const float mu = a * (1.f / F_);
        const float var = q * (1.f / F_) - mu * mu;
        mu_s = mu;
        rs_s = rsqrtf(var + EPSV);
    }
    __syncthreads();
    out[idx] = (v - mu_s) * rs_s * g[t] + bta[t];
}

// -------------------------------------------------------------------------------
extern "C" void kernel_launch(void* const* d_in, const int* in_sizes, int n_in,
                              void* d_out, int out_size, void* d_ws, size_t ws_size,
                              hipStream_t stream)
{
    const float* x     = (const float*)d_in[0];
    const int*   adj   = (const int*)d_in[1];
    const float* W1    = (const float*)d_in[2];
    const float* a1    = (const float*)d_in[3];
    const float* W2    = (const float*)d_in[4];
    const float* a2    = (const float*)d_in[5];
    const float* w_ff1 = (const float*)d_in[6];
    const float* b_ff1 = (const float*)d_in[7];
    const float* w_ff2 = (const float*)d_in[8];
    const float* b_ff2 = (const float*)d_in[9];
    const float* g_ln1 = (const float*)d_in[10];
    const float* b_ln1 = (const float*)d_in[11];
    const float* g_ln2 = (const float*)d_in[12];
    const float* b_ln2 = (const float*)d_in[13];
    float* out = (float*)d_out;

    const int Rtot = B_ * N_;             // 8192
    char* wsb = (char*)d_ws;
    float* part  = (float*)wsb;                                  // 32 MB
    float* ln1   = (float*)(wsb + 33554432);                     // 8 MB
    float* ffout = (float*)(wsb + 41943040);                     // 8 MB
    unsigned short* mid  = (unsigned short*)(wsb + 50331648);    // 16 MB
    unsigned short* ln1b = (unsigned short*)(wsb + 67108864);    // 4 MB
    unsigned short* g1b  = (unsigned short*)(wsb + 71303168);    // 4 MB
    unsigned short* Wht  = (unsigned short*)(wsb + 75497472);    // 4 MB
    unsigned long long* mask = (unsigned long long*)(wsb + 79691776); // 4 MB
    unsigned short* mask16 = (unsigned short*)mask;
    unsigned short* Wt1  = (unsigned short*)(wsb + 83886080);    // 128 KB
    unsigned short* Wt2  = Wt1 + 65536;                          // 128 KB
    unsigned short* Wtf1 = Wt2 + 65536;                          // 512 KB
    unsigned short* Wtf2 = Wtf1 + 262144;                        // 512 KB
    float* WhA1 = (float*)(wsb + 85196800);
    float* WhA2 = WhA1 + 8192;
    float* WhB1 = WhA2 + 8192;
    float* WhB2 = WhB1 + 8192;
    float* Mo   = (float*)(wsb + 85327872);                      // 32 KB
    float* pM   = (float*)(wsb + 85360640);                      // 512 KB
    float* pS   = (float*)(wsb + 85884928);                      // 512 KB

    const dim3 statsG(N_ / 256, SPLIT_, B_);
    const dim3 finG(N_ / 256, B_);
    const dim3 attG(N_ / 64, SPLITJ_, B_);

    // ===== prologue: zero atomic targets, transpose all weights =====
    zero_kernel<<<32, 256, 0, stream>>>(WhA1);   // covers WhA1..WhB2 (32768 f)
    transp_all_kernel<<<dim3(16, 16, 4), 256, 0, stream>>>(
        W1, W2, w_ff1, w_ff2, Wt1, Wt2, Wtf1, Wtf2);

    // ===== GAT layer 1 =====
    gemm128_kernel<<<dim3(2, 64), 256, 0, stream>>>(
        x, Wt1, nullptr, nullptr, Wht, a1, WhA1, WhA2, F_, F_, 0, 0, 0);
    colstats_adj_kernel<<<statsG, 256, 0, stream>>>(adj, mask, WhA1, WhA2, pM, pS);
    colfin2_kernel<<<finG, 256, 0, stream>>>(pM, pS, Mo);
    att_mfma3_kernel<<<attG, 256, 0, stream>>>(mask16, Wht, WhA1, WhA2, Mo, part);
    reduce4b_kernel<<<2048, 256, 0, stream>>>(part, g1b);

    // ===== GAT layer 2 (mask reused) =====
    gemm128_kernel<<<dim3(2, 64), 256, 0, stream>>>(
        g1b, Wt2, nullptr, nullptr, Wht, a2, WhB1, WhB2, F_, F_, 0, 1, 0);
    colstats3_kernel<<<statsG, 256, 0, stream>>>(mask, WhB1, WhB2, pM, pS);
    colfin2_kernel<<<finG, 256, 0, stream>>>(pM, pS, Mo);
    att_mfma3_kernel<<<attG, 256, 0, stream>>>(mask16, Wht, WhB1, WhB2, Mo, part);

    // ===== LN1(x + sum of 4 att partials) -> ln1 fp32 + ln1b bf16 =====
    addln4_kernel<<<Rtot, 256, 0, stream>>>(x, part, g_ln1, b_ln1, ln1, ln1b);

    // ===== FFN =====
    gemm128_kernel<<<dim3(8, 64), 256, 0, stream>>>(
        ln1b, Wtf1, b_ff1, mid, nullptr, nullptr, nullptr, nullptr, H_, F_, 1, 1, 2);
    gemm128_kernel<<<dim3(2, 64), 256, 0, stream>>>(
        mid, Wtf2, b_ff2, ffout, nullptr, nullptr, nullptr, nullptr, F_, H_, 0, 1, 1);

    // ===== LN2(ln1 + ff) =====
    addln_kernel<<<Rtot, 256, 0, stream>>>(ln1, ffout, g_ln2, b_ln2, out);
}